// Round 1
// baseline (1299.833 us; speedup 1.0000x reference)
//
#include <hip/hip_runtime.h>

// S4 model (B=8, L=4096, H=512, N=16, 4 layers), fully fused pipeline:
//   encoder -> 4x [row-stats(LN) -> scan phase1/2/3 (bidir SSM recurrence, fp32)
//                  -> bf16 MFMA GEMM with fused GLU+residual] -> decoder
// Workspace layout (bytes): hbuf[0, 64MB) S[64,96MB) params[+1MB) stats[+0.5MB)
//                           ow_bf16[+4MB) y_bf16[+32MB)  total ~140MB.

typedef __attribute__((ext_vector_type(8))) short s16x8;
typedef __attribute__((ext_vector_type(4))) float f32x4;
typedef unsigned short u16;
typedef unsigned int u32;

#define LSEQ 4096
#define HD   512
#define NST  16
#define NLAYER 4
#define BS   8
#define LC   128
#define NCH  32   // LSEQ / LC

static __device__ __forceinline__ u16 f2bf(float f){
  u32 u = __builtin_bit_cast(u32, f);
  u += 0x7FFFu + ((u >> 16) & 1u);     // round-to-nearest-even (values are finite/normal here)
  return (u16)(u >> 16);
}

// ---------------- per-layer SSM params: w=exp(dt*A), w^LC, Ct=2*C*(w-1)/A ----------
// params layout per layer (65536 floats):
//   [0)      w  : n*1024 + {0,512} + h
//   [16384)  wLc: n*1024 + {0,512} + h
//   [32768)  Ct : (d*16+n)*1024 + {0,512} + h      (includes the factor 2)
__global__ __launch_bounds__(256) void param_kernel(
    const float* __restrict__ log_dt, const float* __restrict__ A_re,
    const float* __restrict__ A_im, const float* __restrict__ C_re,
    const float* __restrict__ C_im, float* __restrict__ params)
{
  int idx = blockIdx.x*256 + threadIdx.x;        // NLAYER*NST*HD = 32768
  int h = idx & (HD-1);
  int n = (idx >> 9) & (NST-1);
  int layer = idx >> 13;
  float dt  = expf(log_dt[layer*HD + h]);
  float Are = A_re[((layer<<9)+h)*NST + n];
  float Aim = A_im[((layer<<9)+h)*NST + n];
  float ar = Are*dt, ai = Aim*dt;
  float er = expf(ar), sn, cs;
  sincosf(ai, &sn, &cs);
  float wr = er*cs, wi = er*sn;
  float eL = expf((float)LC*ar), snL, csL;
  sincosf((float)LC*ai, &snL, &csL);
  float* P = params + layer*65536;
  P[n*1024 + h]        = wr;
  P[n*1024 + 512 + h]  = wi;
  P[16384 + n*1024 + h]       = eL*csL;
  P[16384 + n*1024 + 512 + h] = eL*snL;
  float den = Are*Are + Aim*Aim;
  float qr = ((wr-1.f)*Are + wi*Aim) / den;      // (w-1)/A = (w-1)*conj(A)/|A|^2
  float qi = (wi*Are - (wr-1.f)*Aim) / den;
  #pragma unroll
  for (int d=0; d<2; d++){
    float Cre = C_re[(((layer*2+d)<<9)+h)*NST + n];
    float Cim = C_im[(((layer*2+d)<<9)+h)*NST + n];
    P[32768 + (d*NST+n)*1024 + h]       = 2.f*(Cre*qr - Cim*qi);
    P[32768 + (d*NST+n)*1024 + 512 + h] = 2.f*(Cre*qi + Cim*qr);
  }
}

__global__ __launch_bounds__(256) void owconv_kernel(const float* __restrict__ ow,
                                                     u16* __restrict__ owbf)
{
  size_t idx = (size_t)blockIdx.x*256 + threadIdx.x;   // 4*1024*512 = 2,097,152
  owbf[idx] = f2bf(ow[idx]);
}

// ---------------- encoder: h[b,t,h] = x[b,t]*ew[h,0] + grid[t]*ew[h,1] + eb[h] ------
__global__ __launch_bounds__(256) void encoder_kernel(
    const float* __restrict__ x, const float* __restrict__ ew,
    const float* __restrict__ eb, float* __restrict__ hbuf)
{
  size_t idx = (size_t)blockIdx.x*256 + threadIdx.x;   // B*L*H = 16,777,216
  int h = (int)(idx & (HD-1));
  int t = (int)((idx >> 9) & (LSEQ-1));
  int b = (int)(idx >> 21);
  float g = (float)t * (1.0f/4095.0f);
  hbuf[idx] = x[(b<<12) + t]*ew[2*h] + g*ew[2*h+1] + eb[h];
}

// ---------------- per-row LN stats: mean & rstd over H ------------------------------
__global__ __launch_bounds__(256) void stats_kernel(const float* __restrict__ hbuf,
                                                    float2* __restrict__ stats)
{
  int row  = (int)((blockIdx.x*256 + threadIdx.x) >> 6);  // one wave per row
  int lane = threadIdx.x & 63;
  const float* p = hbuf + ((size_t)row << 9) + lane*8;
  float4 a = *(const float4*)p;
  float4 b = *(const float4*)(p+4);
  float s  = a.x+a.y+a.z+a.w + b.x+b.y+b.z+b.w;
  float sq = a.x*a.x+a.y*a.y+a.z*a.z+a.w*a.w + b.x*b.x+b.y*b.y+b.z*b.z+b.w*b.w;
  #pragma unroll
  for (int off=32; off; off>>=1){ s += __shfl_xor(s, off, 64); sq += __shfl_xor(sq, off, 64); }
  if (lane == 0){
    float mu = s*(1.f/512.f);
    float var = sq*(1.f/512.f) - mu*mu;
    stats[row] = make_float2(mu, rsqrtf(var + 1e-5f));
  }
}

// ---------------- phase 1: chunk summaries (both dirs) ------------------------------
// S layout: (((b*2+dir)*NCH + c)*NST + n)*1024 + {0,512} + h
__global__ __launch_bounds__(64) void phase1_kernel(
    const float* __restrict__ hbuf, const float2* __restrict__ stats,
    const float* __restrict__ lnw, const float* __restrict__ lnb,
    const float* __restrict__ P, float* __restrict__ S)
{
  int bx = blockIdx.x;                  // ((b*2+dir)*32 + c)*8 + hg ; 4096 blocks
  int hg  = bx & 7;
  int c   = (bx >> 3) & 31;
  int dir = (bx >> 8) & 1;
  int b   = bx >> 9;
  int lane = threadIdx.x;
  int hcol = (hg << 6) + lane;
  float wr[NST], wi[NST];
  #pragma unroll
  for (int n=0;n<NST;n++){ wr[n] = P[n*1024 + hcol]; wi[n] = P[n*1024 + 512 + hcol]; }
  float lw = lnw[hcol], lb = lnb[hcol];
  float sr[NST], si[NST];
  #pragma unroll
  for (int n=0;n<NST;n++){ sr[n]=0.f; si[n]=0.f; }
  int t0 = c << 7;
  const float*  hp = hbuf + ((size_t)b << 21) + hcol;
  const float2* sp = stats + ((size_t)b << 12);
  for (int j4=0; j4<LC; j4+=4){
    float uv[4];
    #pragma unroll
    for (int q=0;q<4;q++){
      int j = j4 + q;
      int t = dir ? (t0 + (LC-1) - j) : (t0 + j);
      float hv = hp[(size_t)t << 9];
      float2 st = sp[t];
      uv[q] = (hv - st.x)*st.y*lw + lb;
    }
    #pragma unroll
    for (int q=0;q<4;q++){
      float u = uv[q];
      #pragma unroll
      for (int n=0;n<NST;n++){
        float s0 = sr[n];
        sr[n] = fmaf(wr[n], s0, fmaf(-wi[n], si[n], u));
        si[n] = fmaf(wr[n], si[n], wi[n]*s0);
      }
    }
  }
  size_t sbase = (((size_t)(b*2+dir)*NCH + c)*NST)*1024 + hcol;
  #pragma unroll
  for (int n=0;n<NST;n++){
    S[sbase + (size_t)n*1024]       = sr[n];
    S[sbase + (size_t)n*1024 + 512] = si[n];
  }
}

// ---------------- phase 2: inter-chunk scan (in place on S) -------------------------
// dir0: S[c] := state after chunk c.  dir1: S[c] := boundary state xb[top of chunk c].
__global__ __launch_bounds__(256) void phase2_kernel(const float* __restrict__ P,
                                                     float* __restrict__ S)
{
  int f = blockIdx.x*256 + threadIdx.x;     // B*2*NST*HD = 131072
  int h   = f & (HD-1);
  int n   = (f >> 9) & (NST-1);
  int dir = (f >> 13) & 1;
  int b   = f >> 14;
  float wLr = P[16384 + n*1024 + h];
  float wLi = P[16384 + n*1024 + 512 + h];
  size_t base = (((size_t)(b*2+dir)*NCH)*NST + n)*1024 + h;
  const size_t cs = (size_t)NST*1024;       // 16384 floats per chunk
  float Xr = 0.f, Xi = 0.f;
  if (dir == 0){
    for (int c=0;c<NCH;c++){
      float Sr = S[base + c*cs], Si = S[base + c*cs + 512];
      float nr = fmaf(wLr, Xr, fmaf(-wLi, Xi, Sr));
      float ni = fmaf(wLr, Xi, fmaf( wLi, Xr, Si));
      Xr = nr; Xi = ni;
      S[base + c*cs] = Xr; S[base + c*cs + 512] = Xi;
    }
  } else {
    for (int cc=0;cc<NCH;cc++){
      int c = NCH-1-cc;
      float Sr = S[base + c*cs], Si = S[base + c*cs + 512];
      S[base + c*cs] = Xr; S[base + c*cs + 512] = Xi;   // store boundary BEFORE update
      float nr = fmaf(wLr, Xr, fmaf(-wLi, Xi, Sr));
      float ni = fmaf(wLr, Xi, fmaf( wLi, Xr, Si));
      Xr = nr; Xi = ni;
    }
  }
}

// ---------------- phase 3: intra-chunk replay, both dirs, +u*D, GELU, bf16 ----------
__global__ __launch_bounds__(64) void phase3_kernel(
    const float* __restrict__ hbuf, const float2* __restrict__ stats,
    const float* __restrict__ lnw, const float* __restrict__ lnb,
    const float* __restrict__ Dvec, const float* __restrict__ P,
    const float* __restrict__ S, u16* __restrict__ ybf)
{
  int bx = blockIdx.x;                 // (b*32 + c)*8 + hg ; 2048 blocks
  int hg = bx & 7;
  int c  = (bx >> 3) & 31;
  int b  = bx >> 8;
  int lane = threadIdx.x;
  int hcol = (hg << 6) + lane;
  __shared__ float ylds[LC*64];
  float wr[NST], wi[NST];
  #pragma unroll
  for (int n=0;n<NST;n++){ wr[n] = P[n*1024 + hcol]; wi[n] = P[n*1024 + 512 + hcol]; }
  float lw = lnw[hcol], lb = lnb[hcol], Dh = Dvec[hcol];
  int t0 = c << 7;
  const float*  hp = hbuf + ((size_t)b << 21) + hcol;
  const float2* sp = stats + ((size_t)b << 12);

  // ---- forward ----
  {
    float cr[NST], ci[NST], xr[NST], xi[NST];
    #pragma unroll
    for (int n=0;n<NST;n++){
      cr[n] = P[32768 + n*1024 + hcol];
      ci[n] = P[32768 + n*1024 + 512 + hcol];
    }
    if (c > 0){
      size_t sb = (((size_t)(b*2+0)*NCH + (c-1))*NST)*1024 + hcol;
      #pragma unroll
      for (int n=0;n<NST;n++){ xr[n] = S[sb + (size_t)n*1024]; xi[n] = S[sb + (size_t)n*1024 + 512]; }
    } else {
      #pragma unroll
      for (int n=0;n<NST;n++){ xr[n]=0.f; xi[n]=0.f; }
    }
    for (int j4=0;j4<LC;j4+=4){
      float uv[4];
      #pragma unroll
      for (int q=0;q<4;q++){
        int t = t0 + j4 + q;
        float hv = hp[(size_t)t << 9];
        float2 st = sp[t];
        uv[q] = (hv - st.x)*st.y*lw + lb;
      }
      #pragma unroll
      for (int q=0;q<4;q++){
        float u = uv[q];
        float acc = u*Dh;
        #pragma unroll
        for (int n=0;n<NST;n++){
          float s0 = xr[n];
          xr[n] = fmaf(wr[n], s0, fmaf(-wi[n], xi[n], u));
          xi[n] = fmaf(wr[n], xi[n], wi[n]*s0);
          acc = fmaf(cr[n], xr[n], acc);
          acc = fmaf(-ci[n], xi[n], acc);
        }
        ylds[((j4+q)<<6) + lane] = acc;
      }
    }
  }
  // ---- backward ----
  {
    float cr[NST], ci[NST], xr[NST], xi[NST];
    #pragma unroll
    for (int n=0;n<NST;n++){
      cr[n] = P[32768 + (NST+n)*1024 + hcol];
      ci[n] = P[32768 + (NST+n)*1024 + 512 + hcol];
    }
    size_t sb = (((size_t)(b*2+1)*NCH + c)*NST)*1024 + hcol;
    #pragma unroll
    for (int n=0;n<NST;n++){ xr[n] = S[sb + (size_t)n*1024]; xi[n] = S[sb + (size_t)n*1024 + 512]; }
    for (int j4=0;j4<LC;j4+=4){
      float uv[4];
      #pragma unroll
      for (int q=0;q<4;q++){
        int t = t0 + (LC-1) - (j4+q);
        float hv = hp[(size_t)t << 9];
        float2 st = sp[t];
        uv[q] = (hv - st.x)*st.y*lw + lb;
      }
      #pragma unroll
      for (int q=0;q<4;q++){
        int j = (LC-1) - (j4+q);
        float acc = 0.f;
        #pragma unroll
        for (int n=0;n<NST;n++){
          acc = fmaf(cr[n], xr[n], acc);
          acc = fmaf(-ci[n], xi[n], acc);
        }
        ylds[(j<<6) + lane] += acc;        // emit BEFORE consuming u[t]
        float u = uv[q];
        #pragma unroll
        for (int n=0;n<NST;n++){
          float s0 = xr[n];
          xr[n] = fmaf(wr[n], s0, fmaf(-wi[n], xi[n], u));
          xi[n] = fmaf(wr[n], xi[n], wi[n]*s0);
        }
      }
    }
  }
  // ---- GELU (exact erf) + bf16 store ----
  size_t ybase = ((size_t)b << 21) + ((size_t)t0 << 9) + hcol;
  for (int j=0;j<LC;j++){
    float yv = ylds[(j<<6) + lane];
    float g = 0.5f*yv*(1.f + erff(yv*0.70710678118654752f));
    ybf[ybase + ((size_t)j << 9)] = f2bf(g);
  }
}

// ---------------- GEMM (bf16 MFMA) + bias + GLU + residual into h -------------------
// block: 128 rows x (64 cols of half1 + paired 64 cols of half2). 4 waves, each 32 rows.
__global__ __launch_bounds__(256) void gemm_glu_kernel(
    const u16* __restrict__ ybf, const u16* __restrict__ owbf,
    const float* __restrict__ ob, float* __restrict__ hbuf)
{
  __shared__ u16 As[128*72];
  __shared__ u16 Bsh[128*72];
  const int tid = threadIdx.x;
  const int wave = tid >> 6, lane = tid & 63;
  const int mt = blockIdx.x >> 3, nt = blockIdx.x & 7;
  const int m0 = mt*128, n0 = nt*64;
  f32x4 acc[2][8];
  #pragma unroll
  for (int i=0;i<2;i++)
    #pragma unroll
    for (int j=0;j<8;j++)
      #pragma unroll
      for (int k=0;k<4;k++) acc[i][j][k] = 0.f;

  const int rs = tid >> 3, ch = tid & 7;
  const int ro = lane & 15, qq = lane >> 4;
  for (int k0=0;k0<512;k0+=64){
    __syncthreads();
    #pragma unroll
    for (int p=0;p<4;p++){
      int rr = p*32 + rs;
      uint4 va = *(const uint4*)(ybf + ((size_t)(m0+rr) << 9) + k0 + ch*8);
      *(uint4*)(&As[rr*72 + ch*8]) = va;
      int br = n0 + (rr & 63) + ((rr >> 6) << 9);
      uint4 vb = *(const uint4*)(owbf + ((size_t)br << 9) + k0 + ch*8);
      *(uint4*)(&Bsh[rr*72 + ch*8]) = vb;
    }
    __syncthreads();
    #pragma unroll
    for (int ks=0;ks<2;ks++){
      s16x8 a[2], bf[8];
      #pragma unroll
      for (int mi=0;mi<2;mi++){
        uint4 t = *(const uint4*)(&As[(wave*32 + mi*16 + ro)*72 + ks*32 + qq*8]);
        a[mi] = __builtin_bit_cast(s16x8, t);
      }
      #pragma unroll
      for (int ni=0;ni<8;ni++){
        uint4 t = *(const uint4*)(&Bsh[(ni*16 + ro)*72 + ks*32 + qq*8]);
        bf[ni] = __builtin_bit_cast(s16x8, t);
      }
      #pragma unroll
      for (int mi=0;mi<2;mi++)
        #pragma unroll
        for (int ni=0;ni<8;ni++)
          acc[mi][ni] = __builtin_amdgcn_mfma_f32_16x16x32_bf16(a[mi], bf[ni], acc[mi][ni], 0, 0, 0);
    }
  }
  // epilogue: z1*sigmoid(z2) + residual
  #pragma unroll
  for (int ni=0;ni<4;ni++){
    int col = n0 + ni*16 + ro;
    float b1 = ob[col], b2 = ob[col + 512];
    #pragma unroll
    for (int mi=0;mi<2;mi++){
      f32x4 z1 = acc[mi][ni], z2 = acc[mi][ni+4];
      #pragma unroll
      for (int rg=0;rg<4;rg++){
        int row = m0 + wave*32 + mi*16 + qq*4 + rg;
        float zz1 = z1[rg] + b1;
        float zz2 = z2[rg] + b2;
        float g = zz1 / (1.f + expf(-zz2));
        size_t idx = ((size_t)row << 9) + col;
        hbuf[idx] += g;
      }
    }
  }
}

// ---------------- decoder: out[b,t] = h[b,t,:] . dec_w + dec_b ----------------------
__global__ __launch_bounds__(256) void decoder_kernel(
    const float* __restrict__ hbuf, const float* __restrict__ dec_w,
    const float* __restrict__ dec_b, float* __restrict__ out)
{
  int wid  = (int)((blockIdx.x*256 + threadIdx.x) >> 6);  // row id, 32768 total
  int lane = threadIdx.x & 63;
  const float* p = hbuf + ((size_t)wid << 9) + lane*8;
  float4 a = *(const float4*)p;
  float4 b = *(const float4*)(p+4);
  const float* dw = dec_w + lane*8;
  float4 w0 = *(const float4*)dw;
  float4 w1 = *(const float4*)(dw+4);
  float s = a.x*w0.x + a.y*w0.y + a.z*w0.z + a.w*w0.w
          + b.x*w1.x + b.y*w1.y + b.z*w1.z + b.w*w1.w;
  #pragma unroll
  for (int off=32; off; off>>=1) s += __shfl_xor(s, off, 64);
  if (lane == 0) out[wid] = s + dec_b[0];
}

extern "C" void kernel_launch(void* const* d_in, const int* in_sizes, int n_in,
                              void* d_out, int out_size, void* d_ws, size_t ws_size,
                              hipStream_t stream) {
  const float* x     = (const float*)d_in[0];
  const float* encw  = (const float*)d_in[1];
  const float* encb  = (const float*)d_in[2];
  const float* logdt = (const float*)d_in[3];
  const float* A_re  = (const float*)d_in[4];
  const float* A_im  = (const float*)d_in[5];
  const float* C_re  = (const float*)d_in[6];
  const float* C_im  = (const float*)d_in[7];
  const float* Dv    = (const float*)d_in[8];
  const float* out_w = (const float*)d_in[9];
  const float* out_b = (const float*)d_in[10];
  const float* ln_w  = (const float*)d_in[11];
  const float* ln_b  = (const float*)d_in[12];
  const float* dec_w = (const float*)d_in[13];
  const float* dec_b = (const float*)d_in[14];

  char* ws = (char*)d_ws;
  float*  hbuf   = (float*) (ws);                    // 67,108,864 B
  float*  Sbuf   = (float*) (ws + 67108864);         // 33,554,432 B
  float*  params = (float*) (ws + 100663296);        //  1,048,576 B
  float2* stats  = (float2*)(ws + 101711872);        //    524,288 B
  u16*    owbf   = (u16*)   (ws + 102236160);        //  4,194,304 B
  u16*    ybf    = (u16*)   (ws + 106430464);        // 33,554,432 B  (end 139,984,896)

  param_kernel<<<128, 256, 0, stream>>>(logdt, A_re, A_im, C_re, C_im, params);
  owconv_kernel<<<8192, 256, 0, stream>>>(out_w, owbf);
  encoder_kernel<<<65536, 256, 0, stream>>>(x, encw, encb, hbuf);
  for (int layer=0; layer<NLAYER; ++layer){
    const float* P = params + layer*65536;
    stats_kernel<<<8192, 256, 0, stream>>>(hbuf, stats);
    phase1_kernel<<<4096, 64, 0, stream>>>(hbuf, stats, ln_w + layer*HD, ln_b + layer*HD, P, Sbuf);
    phase2_kernel<<<512, 256, 0, stream>>>(P, Sbuf);
    phase3_kernel<<<2048, 64, 0, stream>>>(hbuf, stats, ln_w + layer*HD, ln_b + layer*HD,
                                           Dv + layer*HD, P, Sbuf, ybf);
    gemm_glu_kernel<<<2048, 256, 0, stream>>>(ybf, owbf + (size_t)layer*524288,
                                              out_b + layer*1024, hbuf);
  }
  decoder_kernel<<<8192, 256, 0, stream>>>(hbuf, dec_w, dec_b, (float*)d_out);
}

// Round 2
// 1226.962 us; speedup vs baseline: 1.0594x; 1.0594x over previous
//
#include <hip/hip_runtime.h>

// S4 model (B=8, L=4096, H=512, N=16, 4 layers), fully fused pipeline:
//   encoder -> 4x [row-stats(LN) -> scan phase1/2/3 (bidir SSM recurrence, fp32)
//                  -> bf16 MFMA GEMM (global_load_lds staging) with fused GLU+residual]
//   -> decoder
// Round 2: phase3 drops its 32KB LDS (occupancy 8%->~50%) by round-tripping the
// forward partial through a fp32 global scratch y32 (same-lane RAW, L2-resident).
// GEMM staging switched to global_load_lds width=16 (m97 recipe).

typedef __attribute__((ext_vector_type(8))) short s16x8;
typedef __attribute__((ext_vector_type(4))) float f32x4;
typedef unsigned short u16;
typedef unsigned int u32;

#define LSEQ 4096
#define HD   512
#define NST  16
#define NLAYER 4
#define BS   8
#define LC   128
#define NCH  32   // LSEQ / LC

static __device__ __forceinline__ u16 f2bf(float f){
  u32 u = __builtin_bit_cast(u32, f);
  u += 0x7FFFu + ((u >> 16) & 1u);     // round-to-nearest-even
  return (u16)(u >> 16);
}

static __device__ __forceinline__ void async16(const void* g, void* l){
  __builtin_amdgcn_global_load_lds((const __attribute__((address_space(1))) unsigned*)g,
                                   (__attribute__((address_space(3))) unsigned*)l,
                                   16, 0, 0);
}

// ---------------- per-layer SSM params: w=exp(dt*A), w^LC, Ct=2*C*(w-1)/A ----------
// params layout per layer (65536 floats):
//   [0)      w  : n*1024 + {0,512} + h
//   [16384)  wLc: n*1024 + {0,512} + h
//   [32768)  Ct : (d*16+n)*1024 + {0,512} + h      (includes the factor 2)
__global__ __launch_bounds__(256) void param_kernel(
    const float* __restrict__ log_dt, const float* __restrict__ A_re,
    const float* __restrict__ A_im, const float* __restrict__ C_re,
    const float* __restrict__ C_im, float* __restrict__ params)
{
  int idx = blockIdx.x*256 + threadIdx.x;        // NLAYER*NST*HD = 32768
  int h = idx & (HD-1);
  int n = (idx >> 9) & (NST-1);
  int layer = idx >> 13;
  float dt  = expf(log_dt[layer*HD + h]);
  float Are = A_re[((layer<<9)+h)*NST + n];
  float Aim = A_im[((layer<<9)+h)*NST + n];
  float ar = Are*dt, ai = Aim*dt;
  float er = expf(ar), sn, cs;
  sincosf(ai, &sn, &cs);
  float wr = er*cs, wi = er*sn;
  float eL = expf((float)LC*ar), snL, csL;
  sincosf((float)LC*ai, &snL, &csL);
  float* P = params + layer*65536;
  P[n*1024 + h]        = wr;
  P[n*1024 + 512 + h]  = wi;
  P[16384 + n*1024 + h]       = eL*csL;
  P[16384 + n*1024 + 512 + h] = eL*snL;
  float den = Are*Are + Aim*Aim;
  float qr = ((wr-1.f)*Are + wi*Aim) / den;      // (w-1)/A = (w-1)*conj(A)/|A|^2
  float qi = (wi*Are - (wr-1.f)*Aim) / den;
  #pragma unroll
  for (int d=0; d<2; d++){
    float Cre = C_re[(((layer*2+d)<<9)+h)*NST + n];
    float Cim = C_im[(((layer*2+d)<<9)+h)*NST + n];
    P[32768 + (d*NST+n)*1024 + h]       = 2.f*(Cre*qr - Cim*qi);
    P[32768 + (d*NST+n)*1024 + 512 + h] = 2.f*(Cre*qi + Cim*qr);
  }
}

__global__ __launch_bounds__(256) void owconv_kernel(const float* __restrict__ ow,
                                                     u16* __restrict__ owbf)
{
  size_t idx = (size_t)blockIdx.x*256 + threadIdx.x;   // 4*1024*512 = 2,097,152
  owbf[idx] = f2bf(ow[idx]);
}

// ---------------- encoder: h[b,t,h] = x[b,t]*ew[h,0] + grid[t]*ew[h,1] + eb[h] ------
__global__ __launch_bounds__(256) void encoder_kernel(
    const float* __restrict__ x, const float* __restrict__ ew,
    const float* __restrict__ eb, float* __restrict__ hbuf)
{
  size_t idx = (size_t)blockIdx.x*256 + threadIdx.x;   // B*L*H = 16,777,216
  int h = (int)(idx & (HD-1));
  int t = (int)((idx >> 9) & (LSEQ-1));
  int b = (int)(idx >> 21);
  float g = (float)t * (1.0f/4095.0f);
  hbuf[idx] = x[(b<<12) + t]*ew[2*h] + g*ew[2*h+1] + eb[h];
}

// ---------------- per-row LN stats: mean & rstd over H ------------------------------
__global__ __launch_bounds__(256) void stats_kernel(const float* __restrict__ hbuf,
                                                    float2* __restrict__ stats)
{
  int row  = (int)((blockIdx.x*256 + threadIdx.x) >> 6);  // one wave per row
  int lane = threadIdx.x & 63;
  const float* p = hbuf + ((size_t)row << 9) + lane*8;
  float4 a = *(const float4*)p;
  float4 b = *(const float4*)(p+4);
  float s  = a.x+a.y+a.z+a.w + b.x+b.y+b.z+b.w;
  float sq = a.x*a.x+a.y*a.y+a.z*a.z+a.w*a.w + b.x*b.x+b.y*b.y+b.z*b.z+b.w*b.w;
  #pragma unroll
  for (int off=32; off; off>>=1){ s += __shfl_xor(s, off, 64); sq += __shfl_xor(sq, off, 64); }
  if (lane == 0){
    float mu = s*(1.f/512.f);
    float var = sq*(1.f/512.f) - mu*mu;
    stats[row] = make_float2(mu, rsqrtf(var + 1e-5f));
  }
}

// ---------------- phase 1: chunk summaries (both dirs) ------------------------------
// S layout: (((b*2+dir)*NCH + c)*NST + n)*1024 + {0,512} + h
__global__ __launch_bounds__(64) void phase1_kernel(
    const float* __restrict__ hbuf, const float2* __restrict__ stats,
    const float* __restrict__ lnw, const float* __restrict__ lnb,
    const float* __restrict__ P, float* __restrict__ S)
{
  int bx = blockIdx.x;                  // ((b*2+dir)*32 + c)*8 + hg ; 4096 blocks
  int hg  = bx & 7;
  int c   = (bx >> 3) & 31;
  int dir = (bx >> 8) & 1;
  int b   = bx >> 9;
  int lane = threadIdx.x;
  int hcol = (hg << 6) + lane;
  float wr[NST], wi[NST];
  #pragma unroll
  for (int n=0;n<NST;n++){ wr[n] = P[n*1024 + hcol]; wi[n] = P[n*1024 + 512 + hcol]; }
  float lw = lnw[hcol], lb = lnb[hcol];
  float sr[NST], si[NST];
  #pragma unroll
  for (int n=0;n<NST;n++){ sr[n]=0.f; si[n]=0.f; }
  int t0 = c << 7;
  const float*  hp = hbuf + ((size_t)b << 21) + hcol;
  const float2* sp = stats + ((size_t)b << 12);
  for (int j4=0; j4<LC; j4+=4){
    float uv[4];
    #pragma unroll
    for (int q=0;q<4;q++){
      int j = j4 + q;
      int t = dir ? (t0 + (LC-1) - j) : (t0 + j);
      float hv = hp[(size_t)t << 9];
      float2 st = sp[t];
      uv[q] = (hv - st.x)*st.y*lw + lb;
    }
    #pragma unroll
    for (int q=0;q<4;q++){
      float u = uv[q];
      #pragma unroll
      for (int n=0;n<NST;n++){
        float s0 = sr[n];
        sr[n] = fmaf(wr[n], s0, fmaf(-wi[n], si[n], u));
        si[n] = fmaf(wr[n], si[n], wi[n]*s0);
      }
    }
  }
  size_t sbase = (((size_t)(b*2+dir)*NCH + c)*NST)*1024 + hcol;
  #pragma unroll
  for (int n=0;n<NST;n++){
    S[sbase + (size_t)n*1024]       = sr[n];
    S[sbase + (size_t)n*1024 + 512] = si[n];
  }
}

// ---------------- phase 2: inter-chunk scan (in place on S) -------------------------
__global__ __launch_bounds__(256) void phase2_kernel(const float* __restrict__ P,
                                                     float* __restrict__ S)
{
  int f = blockIdx.x*256 + threadIdx.x;     // B*2*NST*HD = 131072
  int h   = f & (HD-1);
  int n   = (f >> 9) & (NST-1);
  int dir = (f >> 13) & 1;
  int b   = f >> 14;
  float wLr = P[16384 + n*1024 + h];
  float wLi = P[16384 + n*1024 + 512 + h];
  size_t base = (((size_t)(b*2+dir)*NCH)*NST + n)*1024 + h;
  const size_t cs = (size_t)NST*1024;       // 16384 floats per chunk
  float Xr = 0.f, Xi = 0.f;
  if (dir == 0){
    for (int c=0;c<NCH;c++){
      float Sr = S[base + c*cs], Si = S[base + c*cs + 512];
      float nr = fmaf(wLr, Xr, fmaf(-wLi, Xi, Sr));
      float ni = fmaf(wLr, Xi, fmaf( wLi, Xr, Si));
      Xr = nr; Xi = ni;
      S[base + c*cs] = Xr; S[base + c*cs + 512] = Xi;
    }
  } else {
    for (int cc=0;cc<NCH;cc++){
      int c = NCH-1-cc;
      float Sr = S[base + c*cs], Si = S[base + c*cs + 512];
      S[base + c*cs] = Xr; S[base + c*cs + 512] = Xi;   // boundary BEFORE update
      float nr = fmaf(wLr, Xr, fmaf(-wLi, Xi, Sr));
      float ni = fmaf(wLr, Xi, fmaf( wLi, Xr, Si));
      Xr = nr; Xi = ni;
    }
  }
}

// ---------------- phase 3 (no LDS): fwd writes y32; bwd reads, GELU, bf16 -----------
__global__ __launch_bounds__(64) void phase3_kernel(
    const float* __restrict__ hbuf, const float2* __restrict__ stats,
    const float* __restrict__ lnw, const float* __restrict__ lnb,
    const float* __restrict__ Dvec, const float* __restrict__ P,
    const float* __restrict__ S, float* __restrict__ y32, u16* __restrict__ ybf)
{
  int bx = blockIdx.x;                 // (b*32 + c)*8 + hg ; 2048 blocks
  int hg = bx & 7;
  int c  = (bx >> 3) & 31;
  int b  = bx >> 8;
  int lane = threadIdx.x;
  int hcol = (hg << 6) + lane;
  float wr[NST], wi[NST];
  #pragma unroll
  for (int n=0;n<NST;n++){ wr[n] = P[n*1024 + hcol]; wi[n] = P[n*1024 + 512 + hcol]; }
  float lw = lnw[hcol], lb = lnb[hcol], Dh = Dvec[hcol];
  int t0 = c << 7;
  const float*  hp = hbuf + ((size_t)b << 21) + hcol;
  const float2* sp = stats + ((size_t)b << 12);
  float* yp = y32 + ((size_t)b << 21) + hcol;

  // ---- forward: y32[t] = u*D + 2Re(Ct0 . x[t]) ----
  {
    float cr[NST], ci[NST], xr[NST], xi[NST];
    #pragma unroll
    for (int n=0;n<NST;n++){
      cr[n] = P[32768 + n*1024 + hcol];
      ci[n] = P[32768 + n*1024 + 512 + hcol];
    }
    if (c > 0){
      size_t sb = (((size_t)(b*2+0)*NCH + (c-1))*NST)*1024 + hcol;
      #pragma unroll
      for (int n=0;n<NST;n++){ xr[n] = S[sb + (size_t)n*1024]; xi[n] = S[sb + (size_t)n*1024 + 512]; }
    } else {
      #pragma unroll
      for (int n=0;n<NST;n++){ xr[n]=0.f; xi[n]=0.f; }
    }
    for (int j4=0;j4<LC;j4+=4){
      float uv[4];
      #pragma unroll
      for (int q=0;q<4;q++){
        int t = t0 + j4 + q;
        float hv = hp[(size_t)t << 9];
        float2 st = sp[t];
        uv[q] = (hv - st.x)*st.y*lw + lb;
      }
      #pragma unroll
      for (int q=0;q<4;q++){
        float u = uv[q];
        float acc = u*Dh;
        #pragma unroll
        for (int n=0;n<NST;n++){
          float s0 = xr[n];
          xr[n] = fmaf(wr[n], s0, fmaf(-wi[n], xi[n], u));
          xi[n] = fmaf(wr[n], xi[n], wi[n]*s0);
          acc = fmaf(cr[n], xr[n], acc);
          acc = fmaf(-ci[n], xi[n], acc);
        }
        yp[(size_t)(t0 + j4 + q) << 9] = acc;
      }
    }
  }
  // ---- backward: y = y32[t] + 2Re(Ct1 . xb[t]); GELU; bf16 store ----
  {
    float cr[NST], ci[NST], xr[NST], xi[NST];
    #pragma unroll
    for (int n=0;n<NST;n++){
      cr[n] = P[32768 + (NST+n)*1024 + hcol];
      ci[n] = P[32768 + (NST+n)*1024 + 512 + hcol];
    }
    size_t sb = (((size_t)(b*2+1)*NCH + c)*NST)*1024 + hcol;
    #pragma unroll
    for (int n=0;n<NST;n++){ xr[n] = S[sb + (size_t)n*1024]; xi[n] = S[sb + (size_t)n*1024 + 512]; }
    u16* yo = ybf + ((size_t)b << 21) + hcol;
    for (int j4=0;j4<LC;j4+=4){
      float uv[4], yf[4];
      #pragma unroll
      for (int q=0;q<4;q++){
        int t = t0 + (LC-1) - (j4+q);
        float hv = hp[(size_t)t << 9];
        float2 st = sp[t];
        uv[q] = (hv - st.x)*st.y*lw + lb;
        yf[q] = yp[(size_t)t << 9];
      }
      #pragma unroll
      for (int q=0;q<4;q++){
        int t = t0 + (LC-1) - (j4+q);
        float acc = yf[q];
        #pragma unroll
        for (int n=0;n<NST;n++){
          acc = fmaf(cr[n], xr[n], acc);
          acc = fmaf(-ci[n], xi[n], acc);
        }
        float g = 0.5f*acc*(1.f + erff(acc*0.70710678118654752f));
        yo[(size_t)t << 9] = f2bf(g);
        float u = uv[q];
        #pragma unroll
        for (int n=0;n<NST;n++){
          float s0 = xr[n];
          xr[n] = fmaf(wr[n], s0, fmaf(-wi[n], xi[n], u));
          xi[n] = fmaf(wr[n], xi[n], wi[n]*s0);
        }
      }
    }
  }
}

// ---------------- phase 3 fallback (round-1 LDS version, used if ws too small) ------
__global__ __launch_bounds__(64) void phase3_lds_kernel(
    const float* __restrict__ hbuf, const float2* __restrict__ stats,
    const float* __restrict__ lnw, const float* __restrict__ lnb,
    const float* __restrict__ Dvec, const float* __restrict__ P,
    const float* __restrict__ S, u16* __restrict__ ybf)
{
  int bx = blockIdx.x;
  int hg = bx & 7;
  int c  = (bx >> 3) & 31;
  int b  = bx >> 8;
  int lane = threadIdx.x;
  int hcol = (hg << 6) + lane;
  __shared__ float ylds[LC*64];
  float wr[NST], wi[NST];
  #pragma unroll
  for (int n=0;n<NST;n++){ wr[n] = P[n*1024 + hcol]; wi[n] = P[n*1024 + 512 + hcol]; }
  float lw = lnw[hcol], lb = lnb[hcol], Dh = Dvec[hcol];
  int t0 = c << 7;
  const float*  hp = hbuf + ((size_t)b << 21) + hcol;
  const float2* sp = stats + ((size_t)b << 12);
  {
    float cr[NST], ci[NST], xr[NST], xi[NST];
    #pragma unroll
    for (int n=0;n<NST;n++){
      cr[n] = P[32768 + n*1024 + hcol];
      ci[n] = P[32768 + n*1024 + 512 + hcol];
    }
    if (c > 0){
      size_t sb = (((size_t)(b*2+0)*NCH + (c-1))*NST)*1024 + hcol;
      #pragma unroll
      for (int n=0;n<NST;n++){ xr[n] = S[sb + (size_t)n*1024]; xi[n] = S[sb + (size_t)n*1024 + 512]; }
    } else {
      #pragma unroll
      for (int n=0;n<NST;n++){ xr[n]=0.f; xi[n]=0.f; }
    }
    for (int j4=0;j4<LC;j4+=4){
      float uv[4];
      #pragma unroll
      for (int q=0;q<4;q++){
        int t = t0 + j4 + q;
        float hv = hp[(size_t)t << 9];
        float2 st = sp[t];
        uv[q] = (hv - st.x)*st.y*lw + lb;
      }
      #pragma unroll
      for (int q=0;q<4;q++){
        float u = uv[q];
        float acc = u*Dh;
        #pragma unroll
        for (int n=0;n<NST;n++){
          float s0 = xr[n];
          xr[n] = fmaf(wr[n], s0, fmaf(-wi[n], xi[n], u));
          xi[n] = fmaf(wr[n], xi[n], wi[n]*s0);
          acc = fmaf(cr[n], xr[n], acc);
          acc = fmaf(-ci[n], xi[n], acc);
        }
        ylds[((j4+q)<<6) + lane] = acc;
      }
    }
  }
  {
    float cr[NST], ci[NST], xr[NST], xi[NST];
    #pragma unroll
    for (int n=0;n<NST;n++){
      cr[n] = P[32768 + (NST+n)*1024 + hcol];
      ci[n] = P[32768 + (NST+n)*1024 + 512 + hcol];
    }
    size_t sb = (((size_t)(b*2+1)*NCH + c)*NST)*1024 + hcol;
    #pragma unroll
    for (int n=0;n<NST;n++){ xr[n] = S[sb + (size_t)n*1024]; xi[n] = S[sb + (size_t)n*1024 + 512]; }
    for (int j4=0;j4<LC;j4+=4){
      float uv[4];
      #pragma unroll
      for (int q=0;q<4;q++){
        int t = t0 + (LC-1) - (j4+q);
        float hv = hp[(size_t)t << 9];
        float2 st = sp[t];
        uv[q] = (hv - st.x)*st.y*lw + lb;
      }
      #pragma unroll
      for (int q=0;q<4;q++){
        int j = (LC-1) - (j4+q);
        float acc = 0.f;
        #pragma unroll
        for (int n=0;n<NST;n++){
          acc = fmaf(cr[n], xr[n], acc);
          acc = fmaf(-ci[n], xi[n], acc);
        }
        ylds[(j<<6) + lane] += acc;
        float u = uv[q];
        #pragma unroll
        for (int n=0;n<NST;n++){
          float s0 = xr[n];
          xr[n] = fmaf(wr[n], s0, fmaf(-wi[n], xi[n], u));
          xi[n] = fmaf(wr[n], xi[n], wi[n]*s0);
        }
      }
    }
  }
  size_t ybase = ((size_t)b << 21) + ((size_t)t0 << 9) + hcol;
  for (int j=0;j<LC;j++){
    float yv = ylds[(j<<6) + lane];
    float g = 0.5f*yv*(1.f + erff(yv*0.70710678118654752f));
    ybf[ybase + ((size_t)j << 9)] = f2bf(g);
  }
}

// ---------------- GEMM (bf16 MFMA, global_load_lds staging) + GLU + residual --------
// block: 128 rows x 64 col-pairs (cols n0..n0+63 and n0+512..). 4 waves x 32 rows.
__global__ __launch_bounds__(256) void gemm_glu_kernel(
    const u16* __restrict__ ybf, const u16* __restrict__ owbf,
    const float* __restrict__ ob, float* __restrict__ hbuf)
{
  __shared__ u16 As[128*64];    // pitch 64 u16 = 128B, unpadded (lane-linear for DMA)
  __shared__ u16 Bsh[128*64];
  const int tid = threadIdx.x;
  const int wave = tid >> 6, lane = tid & 63;
  const int mt = blockIdx.x >> 3, nt = blockIdx.x & 7;
  const int m0 = mt*128, n0 = nt*64;
  const int row = tid >> 3;           // 0..31
  const int ch8 = (tid & 7) << 3;     // 0,8,...,56 (u16 units)
  f32x4 acc[2][8];
  #pragma unroll
  for (int i=0;i<2;i++)
    #pragma unroll
    for (int j=0;j<8;j++)
      #pragma unroll
      for (int k=0;k<4;k++) acc[i][j][k] = 0.f;

  const int ro = lane & 15, qq = lane >> 4;
  for (int k0=0;k0<512;k0+=64){
    __syncthreads();
    #pragma unroll
    for (int p=0;p<4;p++){
      int r = p*32 + row;
      async16(ybf + ((size_t)(m0+r) << 9) + k0 + ch8, &As[(r<<6) + ch8]);
      int br = n0 + (r & 63) + ((r >> 6) << 9);
      async16(owbf + ((size_t)br << 9) + k0 + ch8, &Bsh[(r<<6) + ch8]);
    }
    __syncthreads();
    #pragma unroll
    for (int ks=0;ks<2;ks++){
      s16x8 a[2], bf[8];
      #pragma unroll
      for (int mi=0;mi<2;mi++){
        uint4 t = *(const uint4*)(&As[(wave*32 + mi*16 + ro)*64 + ks*32 + qq*8]);
        a[mi] = __builtin_bit_cast(s16x8, t);
      }
      #pragma unroll
      for (int ni=0;ni<8;ni++){
        uint4 t = *(const uint4*)(&Bsh[(ni*16 + ro)*64 + ks*32 + qq*8]);
        bf[ni] = __builtin_bit_cast(s16x8, t);
      }
      #pragma unroll
      for (int mi=0;mi<2;mi++)
        #pragma unroll
        for (int ni=0;ni<8;ni++)
          acc[mi][ni] = __builtin_amdgcn_mfma_f32_16x16x32_bf16(a[mi], bf[ni], acc[mi][ni], 0, 0, 0);
    }
  }
  // epilogue: z1*sigmoid(z2) + residual
  #pragma unroll
  for (int ni=0;ni<4;ni++){
    int col = n0 + ni*16 + ro;
    float b1 = ob[col], b2 = ob[col + 512];
    #pragma unroll
    for (int mi=0;mi<2;mi++){
      f32x4 z1 = acc[mi][ni], z2 = acc[mi][ni+4];
      #pragma unroll
      for (int rg=0;rg<4;rg++){
        int rowi = m0 + wave*32 + mi*16 + qq*4 + rg;
        float zz1 = z1[rg] + b1;
        float zz2 = z2[rg] + b2;
        float g = zz1 / (1.f + expf(-zz2));
        size_t idx = ((size_t)rowi << 9) + col;
        hbuf[idx] += g;
      }
    }
  }
}

// ---------------- decoder: out[b,t] = h[b,t,:] . dec_w + dec_b ----------------------
__global__ __launch_bounds__(256) void decoder_kernel(
    const float* __restrict__ hbuf, const float* __restrict__ dec_w,
    const float* __restrict__ dec_b, float* __restrict__ out)
{
  int wid  = (int)((blockIdx.x*256 + threadIdx.x) >> 6);  // row id, 32768 total
  int lane = threadIdx.x & 63;
  const float* p = hbuf + ((size_t)wid << 9) + lane*8;
  float4 a = *(const float4*)p;
  float4 b = *(const float4*)(p+4);
  const float* dw = dec_w + lane*8;
  float4 w0 = *(const float4*)dw;
  float4 w1 = *(const float4*)(dw+4);
  float s = a.x*w0.x + a.y*w0.y + a.z*w0.z + a.w*w0.w
          + b.x*w1.x + b.y*w1.y + b.z*w1.z + b.w*w1.w;
  #pragma unroll
  for (int off=32; off; off>>=1) s += __shfl_xor(s, off, 64);
  if (lane == 0) out[wid] = s + dec_b[0];
}

extern "C" void kernel_launch(void* const* d_in, const int* in_sizes, int n_in,
                              void* d_out, int out_size, void* d_ws, size_t ws_size,
                              hipStream_t stream) {
  const float* x     = (const float*)d_in[0];
  const float* encw  = (const float*)d_in[1];
  const float* encb  = (const float*)d_in[2];
  const float* logdt = (const float*)d_in[3];
  const float* A_re  = (const float*)d_in[4];
  const float* A_im  = (const float*)d_in[5];
  const float* C_re  = (const float*)d_in[6];
  const float* C_im  = (const float*)d_in[7];
  const float* Dv    = (const float*)d_in[8];
  const float* out_w = (const float*)d_in[9];
  const float* out_b = (const float*)d_in[10];
  const float* ln_w  = (const float*)d_in[11];
  const float* ln_b  = (const float*)d_in[12];
  const float* dec_w = (const float*)d_in[13];
  const float* dec_b = (const float*)d_in[14];

  char* ws = (char*)d_ws;
  float*  hbuf   = (float*) (ws);                    // 67,108,864 B
  float*  Sbuf   = (float*) (ws + 67108864);         // 33,554,432 B
  float*  params = (float*) (ws + 100663296);        //  1,048,576 B
  float2* stats  = (float2*)(ws + 101711872);        //    524,288 B
  u16*    owbf   = (u16*)   (ws + 102236160);        //  4,194,304 B
  u16*    ybf    = (u16*)   (ws + 106430464);        // 33,554,432 B  (end 139,984,896)
  float*  y32    = (float*) (ws + 139984896);        // 67,108,864 B  (end 207,093,760)
  const bool big_ws = (ws_size >= (size_t)207093760);

  param_kernel<<<128, 256, 0, stream>>>(logdt, A_re, A_im, C_re, C_im, params);
  owconv_kernel<<<8192, 256, 0, stream>>>(out_w, owbf);
  encoder_kernel<<<65536, 256, 0, stream>>>(x, encw, encb, hbuf);
  for (int layer=0; layer<NLAYER; ++layer){
    const float* P = params + layer*65536;
    stats_kernel<<<8192, 256, 0, stream>>>(hbuf, stats);
    phase1_kernel<<<4096, 64, 0, stream>>>(hbuf, stats, ln_w + layer*HD, ln_b + layer*HD, P, Sbuf);
    phase2_kernel<<<512, 256, 0, stream>>>(P, Sbuf);
    if (big_ws){
      phase3_kernel<<<2048, 64, 0, stream>>>(hbuf, stats, ln_w + layer*HD, ln_b + layer*HD,
                                             Dv + layer*HD, P, Sbuf, y32, ybf);
    } else {
      phase3_lds_kernel<<<2048, 64, 0, stream>>>(hbuf, stats, ln_w + layer*HD, ln_b + layer*HD,
                                                 Dv + layer*HD, P, Sbuf, ybf);
    }
    gemm_glu_kernel<<<2048, 256, 0, stream>>>(ybf, owbf + (size_t)layer*524288,
                                              out_b + layer*1024, hbuf);
  }
  decoder_kernel<<<8192, 256, 0, stream>>>(hbuf, dec_w, dec_b, (float*)d_out);
}

// Round 3
// 1165.297 us; speedup vs baseline: 1.1155x; 1.0529x over previous
//
#include <hip/hip_runtime.h>

// S4 model (B=8, L=4096, H=512, N=16, 4 layers), fully fused pipeline.
// Round 3: LC 128->64, NCH 32->64. Doubles scan-phase wave counts (phase3 was
// grid-limited at 8 waves/CU, VALUBusy 50%). phase2/S traffic doubles (accepted).

typedef __attribute__((ext_vector_type(8))) short s16x8;
typedef __attribute__((ext_vector_type(4))) float f32x4;
typedef unsigned short u16;
typedef unsigned int u32;

#define LSEQ 4096
#define HD   512
#define NST  16
#define NLAYER 4
#define BS   8
#define LC   64
#define NCH  64   // LSEQ / LC

static __device__ __forceinline__ u16 f2bf(float f){
  u32 u = __builtin_bit_cast(u32, f);
  u += 0x7FFFu + ((u >> 16) & 1u);     // round-to-nearest-even
  return (u16)(u >> 16);
}

static __device__ __forceinline__ void async16(const void* g, void* l){
  __builtin_amdgcn_global_load_lds((const __attribute__((address_space(1))) unsigned*)g,
                                   (__attribute__((address_space(3))) unsigned*)l,
                                   16, 0, 0);
}

// ---------------- per-layer SSM params: w=exp(dt*A), w^LC, Ct=2*C*(w-1)/A ----------
// params layout per layer (65536 floats):
//   [0)      w  : n*1024 + {0,512} + h
//   [16384)  wLc: n*1024 + {0,512} + h
//   [32768)  Ct : (d*16+n)*1024 + {0,512} + h      (includes the factor 2)
__global__ __launch_bounds__(256) void param_kernel(
    const float* __restrict__ log_dt, const float* __restrict__ A_re,
    const float* __restrict__ A_im, const float* __restrict__ C_re,
    const float* __restrict__ C_im, float* __restrict__ params)
{
  int idx = blockIdx.x*256 + threadIdx.x;        // NLAYER*NST*HD = 32768
  int h = idx & (HD-1);
  int n = (idx >> 9) & (NST-1);
  int layer = idx >> 13;
  float dt  = expf(log_dt[layer*HD + h]);
  float Are = A_re[((layer<<9)+h)*NST + n];
  float Aim = A_im[((layer<<9)+h)*NST + n];
  float ar = Are*dt, ai = Aim*dt;
  float er = expf(ar), sn, cs;
  sincosf(ai, &sn, &cs);
  float wr = er*cs, wi = er*sn;
  float eL = expf((float)LC*ar), snL, csL;
  sincosf((float)LC*ai, &snL, &csL);
  float* P = params + layer*65536;
  P[n*1024 + h]        = wr;
  P[n*1024 + 512 + h]  = wi;
  P[16384 + n*1024 + h]       = eL*csL;
  P[16384 + n*1024 + 512 + h] = eL*snL;
  float den = Are*Are + Aim*Aim;
  float qr = ((wr-1.f)*Are + wi*Aim) / den;      // (w-1)/A = (w-1)*conj(A)/|A|^2
  float qi = (wi*Are - (wr-1.f)*Aim) / den;
  #pragma unroll
  for (int d=0; d<2; d++){
    float Cre = C_re[(((layer*2+d)<<9)+h)*NST + n];
    float Cim = C_im[(((layer*2+d)<<9)+h)*NST + n];
    P[32768 + (d*NST+n)*1024 + h]       = 2.f*(Cre*qr - Cim*qi);
    P[32768 + (d*NST+n)*1024 + 512 + h] = 2.f*(Cre*qi + Cim*qr);
  }
}

__global__ __launch_bounds__(256) void owconv_kernel(const float* __restrict__ ow,
                                                     u16* __restrict__ owbf)
{
  size_t idx = (size_t)blockIdx.x*256 + threadIdx.x;   // 4*1024*512 = 2,097,152
  owbf[idx] = f2bf(ow[idx]);
}

// ---------------- encoder ----------------------------------------------------------
__global__ __launch_bounds__(256) void encoder_kernel(
    const float* __restrict__ x, const float* __restrict__ ew,
    const float* __restrict__ eb, float* __restrict__ hbuf)
{
  size_t idx = (size_t)blockIdx.x*256 + threadIdx.x;   // B*L*H = 16,777,216
  int h = (int)(idx & (HD-1));
  int t = (int)((idx >> 9) & (LSEQ-1));
  int b = (int)(idx >> 21);
  float g = (float)t * (1.0f/4095.0f);
  hbuf[idx] = x[(b<<12) + t]*ew[2*h] + g*ew[2*h+1] + eb[h];
}

// ---------------- per-row LN stats -------------------------------------------------
__global__ __launch_bounds__(256) void stats_kernel(const float* __restrict__ hbuf,
                                                    float2* __restrict__ stats)
{
  int row  = (int)((blockIdx.x*256 + threadIdx.x) >> 6);  // one wave per row
  int lane = threadIdx.x & 63;
  const float* p = hbuf + ((size_t)row << 9) + lane*8;
  float4 a = *(const float4*)p;
  float4 b = *(const float4*)(p+4);
  float s  = a.x+a.y+a.z+a.w + b.x+b.y+b.z+b.w;
  float sq = a.x*a.x+a.y*a.y+a.z*a.z+a.w*a.w + b.x*b.x+b.y*b.y+b.z*b.z+b.w*b.w;
  #pragma unroll
  for (int off=32; off; off>>=1){ s += __shfl_xor(s, off, 64); sq += __shfl_xor(sq, off, 64); }
  if (lane == 0){
    float mu = s*(1.f/512.f);
    float var = sq*(1.f/512.f) - mu*mu;
    stats[row] = make_float2(mu, rsqrtf(var + 1e-5f));
  }
}

// ---------------- phase 1: chunk summaries (both dirs) ------------------------------
// S layout: (((b*2+dir)*NCH + c)*NST + n)*1024 + {0,512} + h
__global__ __launch_bounds__(64) void phase1_kernel(
    const float* __restrict__ hbuf, const float2* __restrict__ stats,
    const float* __restrict__ lnw, const float* __restrict__ lnb,
    const float* __restrict__ P, float* __restrict__ S)
{
  int bx = blockIdx.x;                  // ((b*2+dir)*NCH + c)*8 + hg ; 8192 blocks
  int hg  = bx & 7;
  int c   = (bx >> 3) & (NCH-1);
  int dir = (bx >> 9) & 1;
  int b   = bx >> 10;
  int lane = threadIdx.x;
  int hcol = (hg << 6) + lane;
  float wr[NST], wi[NST];
  #pragma unroll
  for (int n=0;n<NST;n++){ wr[n] = P[n*1024 + hcol]; wi[n] = P[n*1024 + 512 + hcol]; }
  float lw = lnw[hcol], lb = lnb[hcol];
  float sr[NST], si[NST];
  #pragma unroll
  for (int n=0;n<NST;n++){ sr[n]=0.f; si[n]=0.f; }
  int t0 = c * LC;
  const float*  hp = hbuf + ((size_t)b << 21) + hcol;
  const float2* sp = stats + ((size_t)b << 12);
  for (int j4=0; j4<LC; j4+=4){
    float uv[4];
    #pragma unroll
    for (int q=0;q<4;q++){
      int j = j4 + q;
      int t = dir ? (t0 + (LC-1) - j) : (t0 + j);
      float hv = hp[(size_t)t << 9];
      float2 st = sp[t];
      uv[q] = (hv - st.x)*st.y*lw + lb;
    }
    #pragma unroll
    for (int q=0;q<4;q++){
      float u = uv[q];
      #pragma unroll
      for (int n=0;n<NST;n++){
        float s0 = sr[n];
        sr[n] = fmaf(wr[n], s0, fmaf(-wi[n], si[n], u));
        si[n] = fmaf(wr[n], si[n], wi[n]*s0);
      }
    }
  }
  size_t sbase = (((size_t)(b*2+dir)*NCH + c)*NST)*1024 + hcol;
  #pragma unroll
  for (int n=0;n<NST;n++){
    S[sbase + (size_t)n*1024]       = sr[n];
    S[sbase + (size_t)n*1024 + 512] = si[n];
  }
}

// ---------------- phase 2: inter-chunk scan (in place on S) -------------------------
__global__ __launch_bounds__(256) void phase2_kernel(const float* __restrict__ P,
                                                     float* __restrict__ S)
{
  int f = blockIdx.x*256 + threadIdx.x;     // B*2*NST*HD = 131072
  int h   = f & (HD-1);
  int n   = (f >> 9) & (NST-1);
  int dir = (f >> 13) & 1;
  int b   = f >> 14;
  float wLr = P[16384 + n*1024 + h];
  float wLi = P[16384 + n*1024 + 512 + h];
  size_t base = (((size_t)(b*2+dir)*NCH)*NST + n)*1024 + h;
  const size_t cs = (size_t)NST*1024;       // floats per chunk
  float Xr = 0.f, Xi = 0.f;
  if (dir == 0){
    for (int c=0;c<NCH;c++){
      float Sr = S[base + c*cs], Si = S[base + c*cs + 512];
      float nr = fmaf(wLr, Xr, fmaf(-wLi, Xi, Sr));
      float ni = fmaf(wLr, Xi, fmaf( wLi, Xr, Si));
      Xr = nr; Xi = ni;
      S[base + c*cs] = Xr; S[base + c*cs + 512] = Xi;
    }
  } else {
    for (int cc=0;cc<NCH;cc++){
      int c = NCH-1-cc;
      float Sr = S[base + c*cs], Si = S[base + c*cs + 512];
      S[base + c*cs] = Xr; S[base + c*cs + 512] = Xi;   // boundary BEFORE update
      float nr = fmaf(wLr, Xr, fmaf(-wLi, Xi, Sr));
      float ni = fmaf(wLr, Xi, fmaf( wLi, Xr, Si));
      Xr = nr; Xi = ni;
    }
  }
}

// ---------------- phase 3 (no LDS): fwd writes y32; bwd reads, GELU, bf16 -----------
__global__ __launch_bounds__(64) void phase3_kernel(
    const float* __restrict__ hbuf, const float2* __restrict__ stats,
    const float* __restrict__ lnw, const float* __restrict__ lnb,
    const float* __restrict__ Dvec, const float* __restrict__ P,
    const float* __restrict__ S, float* __restrict__ y32, u16* __restrict__ ybf)
{
  int bx = blockIdx.x;                 // (b*NCH + c)*8 + hg ; 4096 blocks
  int hg = bx & 7;
  int c  = (bx >> 3) & (NCH-1);
  int b  = bx >> 9;
  int lane = threadIdx.x;
  int hcol = (hg << 6) + lane;
  float wr[NST], wi[NST];
  #pragma unroll
  for (int n=0;n<NST;n++){ wr[n] = P[n*1024 + hcol]; wi[n] = P[n*1024 + 512 + hcol]; }
  float lw = lnw[hcol], lb = lnb[hcol], Dh = Dvec[hcol];
  int t0 = c * LC;
  const float*  hp = hbuf + ((size_t)b << 21) + hcol;
  const float2* sp = stats + ((size_t)b << 12);
  float* yp = y32 + ((size_t)b << 21) + hcol;

  // ---- forward: y32[t] = u*D + 2Re(Ct0 . x[t]) ----
  {
    float cr[NST], ci[NST], xr[NST], xi[NST];
    #pragma unroll
    for (int n=0;n<NST;n++){
      cr[n] = P[32768 + n*1024 + hcol];
      ci[n] = P[32768 + n*1024 + 512 + hcol];
    }
    if (c > 0){
      size_t sb = (((size_t)(b*2+0)*NCH + (c-1))*NST)*1024 + hcol;
      #pragma unroll
      for (int n=0;n<NST;n++){ xr[n] = S[sb + (size_t)n*1024]; xi[n] = S[sb + (size_t)n*1024 + 512]; }
    } else {
      #pragma unroll
      for (int n=0;n<NST;n++){ xr[n]=0.f; xi[n]=0.f; }
    }
    for (int j4=0;j4<LC;j4+=4){
      float uv[4];
      #pragma unroll
      for (int q=0;q<4;q++){
        int t = t0 + j4 + q;
        float hv = hp[(size_t)t << 9];
        float2 st = sp[t];
        uv[q] = (hv - st.x)*st.y*lw + lb;
      }
      #pragma unroll
      for (int q=0;q<4;q++){
        float u = uv[q];
        float acc = u*Dh;
        #pragma unroll
        for (int n=0;n<NST;n++){
          float s0 = xr[n];
          xr[n] = fmaf(wr[n], s0, fmaf(-wi[n], xi[n], u));
          xi[n] = fmaf(wr[n], xi[n], wi[n]*s0);
          acc = fmaf(cr[n], xr[n], acc);
          acc = fmaf(-ci[n], xi[n], acc);
        }
        yp[(size_t)(t0 + j4 + q) << 9] = acc;
      }
    }
  }
  // ---- backward: y = y32[t] + 2Re(Ct1 . xb[t]); GELU; bf16 store ----
  {
    float cr[NST], ci[NST], xr[NST], xi[NST];
    #pragma unroll
    for (int n=0;n<NST;n++){
      cr[n] = P[32768 + (NST+n)*1024 + hcol];
      ci[n] = P[32768 + (NST+n)*1024 + 512 + hcol];
    }
    size_t sb = (((size_t)(b*2+1)*NCH + c)*NST)*1024 + hcol;
    #pragma unroll
    for (int n=0;n<NST;n++){ xr[n] = S[sb + (size_t)n*1024]; xi[n] = S[sb + (size_t)n*1024 + 512]; }
    u16* yo = ybf + ((size_t)b << 21) + hcol;
    for (int j4=0;j4<LC;j4+=4){
      float uv[4], yf[4];
      #pragma unroll
      for (int q=0;q<4;q++){
        int t = t0 + (LC-1) - (j4+q);
        float hv = hp[(size_t)t << 9];
        float2 st = sp[t];
        uv[q] = (hv - st.x)*st.y*lw + lb;
        yf[q] = yp[(size_t)t << 9];
      }
      #pragma unroll
      for (int q=0;q<4;q++){
        int t = t0 + (LC-1) - (j4+q);
        float acc = yf[q];
        #pragma unroll
        for (int n=0;n<NST;n++){
          acc = fmaf(cr[n], xr[n], acc);
          acc = fmaf(-ci[n], xi[n], acc);
        }
        float g = 0.5f*acc*(1.f + erff(acc*0.70710678118654752f));
        yo[(size_t)t << 9] = f2bf(g);
        float u = uv[q];
        #pragma unroll
        for (int n=0;n<NST;n++){
          float s0 = xr[n];
          xr[n] = fmaf(wr[n], s0, fmaf(-wi[n], xi[n], u));
          xi[n] = fmaf(wr[n], xi[n], wi[n]*s0);
        }
      }
    }
  }
}

// ---------------- phase 3 fallback (LDS partial, 16KB) ------------------------------
__global__ __launch_bounds__(64) void phase3_lds_kernel(
    const float* __restrict__ hbuf, const float2* __restrict__ stats,
    const float* __restrict__ lnw, const float* __restrict__ lnb,
    const float* __restrict__ Dvec, const float* __restrict__ P,
    const float* __restrict__ S, u16* __restrict__ ybf)
{
  int bx = blockIdx.x;
  int hg = bx & 7;
  int c  = (bx >> 3) & (NCH-1);
  int b  = bx >> 9;
  int lane = threadIdx.x;
  int hcol = (hg << 6) + lane;
  __shared__ float ylds[LC*64];
  float wr[NST], wi[NST];
  #pragma unroll
  for (int n=0;n<NST;n++){ wr[n] = P[n*1024 + hcol]; wi[n] = P[n*1024 + 512 + hcol]; }
  float lw = lnw[hcol], lb = lnb[hcol], Dh = Dvec[hcol];
  int t0 = c * LC;
  const float*  hp = hbuf + ((size_t)b << 21) + hcol;
  const float2* sp = stats + ((size_t)b << 12);
  {
    float cr[NST], ci[NST], xr[NST], xi[NST];
    #pragma unroll
    for (int n=0;n<NST;n++){
      cr[n] = P[32768 + n*1024 + hcol];
      ci[n] = P[32768 + n*1024 + 512 + hcol];
    }
    if (c > 0){
      size_t sb = (((size_t)(b*2+0)*NCH + (c-1))*NST)*1024 + hcol;
      #pragma unroll
      for (int n=0;n<NST;n++){ xr[n] = S[sb + (size_t)n*1024]; xi[n] = S[sb + (size_t)n*1024 + 512]; }
    } else {
      #pragma unroll
      for (int n=0;n<NST;n++){ xr[n]=0.f; xi[n]=0.f; }
    }
    for (int j4=0;j4<LC;j4+=4){
      float uv[4];
      #pragma unroll
      for (int q=0;q<4;q++){
        int t = t0 + j4 + q;
        float hv = hp[(size_t)t << 9];
        float2 st = sp[t];
        uv[q] = (hv - st.x)*st.y*lw + lb;
      }
      #pragma unroll
      for (int q=0;q<4;q++){
        float u = uv[q];
        float acc = u*Dh;
        #pragma unroll
        for (int n=0;n<NST;n++){
          float s0 = xr[n];
          xr[n] = fmaf(wr[n], s0, fmaf(-wi[n], xi[n], u));
          xi[n] = fmaf(wr[n], xi[n], wi[n]*s0);
          acc = fmaf(cr[n], xr[n], acc);
          acc = fmaf(-ci[n], xi[n], acc);
        }
        ylds[((j4+q)<<6) + lane] = acc;
      }
    }
  }
  {
    float cr[NST], ci[NST], xr[NST], xi[NST];
    #pragma unroll
    for (int n=0;n<NST;n++){
      cr[n] = P[32768 + (NST+n)*1024 + hcol];
      ci[n] = P[32768 + (NST+n)*1024 + 512 + hcol];
    }
    size_t sb = (((size_t)(b*2+1)*NCH + c)*NST)*1024 + hcol;
    #pragma unroll
    for (int n=0;n<NST;n++){ xr[n] = S[sb + (size_t)n*1024]; xi[n] = S[sb + (size_t)n*1024 + 512]; }
    for (int j4=0;j4<LC;j4+=4){
      float uv[4];
      #pragma unroll
      for (int q=0;q<4;q++){
        int t = t0 + (LC-1) - (j4+q);
        float hv = hp[(size_t)t << 9];
        float2 st = sp[t];
        uv[q] = (hv - st.x)*st.y*lw + lb;
      }
      #pragma unroll
      for (int q=0;q<4;q++){
        int j = (LC-1) - (j4+q);
        float acc = 0.f;
        #pragma unroll
        for (int n=0;n<NST;n++){
          acc = fmaf(cr[n], xr[n], acc);
          acc = fmaf(-ci[n], xi[n], acc);
        }
        ylds[(j<<6) + lane] += acc;
        float u = uv[q];
        #pragma unroll
        for (int n=0;n<NST;n++){
          float s0 = xr[n];
          xr[n] = fmaf(wr[n], s0, fmaf(-wi[n], xi[n], u));
          xi[n] = fmaf(wr[n], xi[n], wi[n]*s0);
        }
      }
    }
  }
  size_t ybase = ((size_t)b << 21) + ((size_t)t0 << 9) + hcol;
  for (int j=0;j<LC;j++){
    float yv = ylds[(j<<6) + lane];
    float g = 0.5f*yv*(1.f + erff(yv*0.70710678118654752f));
    ybf[ybase + ((size_t)j << 9)] = f2bf(g);
  }
}

// ---------------- GEMM (bf16 MFMA, global_load_lds staging) + GLU + residual --------
__global__ __launch_bounds__(256) void gemm_glu_kernel(
    const u16* __restrict__ ybf, const u16* __restrict__ owbf,
    const float* __restrict__ ob, float* __restrict__ hbuf)
{
  __shared__ u16 As[128*64];    // pitch 64 u16 = 128B, unpadded (lane-linear for DMA)
  __shared__ u16 Bsh[128*64];
  const int tid = threadIdx.x;
  const int wave = tid >> 6, lane = tid & 63;
  const int mt = blockIdx.x >> 3, nt = blockIdx.x & 7;
  const int m0 = mt*128, n0 = nt*64;
  const int row = tid >> 3;           // 0..31
  const int ch8 = (tid & 7) << 3;     // 0,8,...,56 (u16 units)
  f32x4 acc[2][8];
  #pragma unroll
  for (int i=0;i<2;i++)
    #pragma unroll
    for (int j=0;j<8;j++)
      #pragma unroll
      for (int k=0;k<4;k++) acc[i][j][k] = 0.f;

  const int ro = lane & 15, qq = lane >> 4;
  for (int k0=0;k0<512;k0+=64){
    __syncthreads();
    #pragma unroll
    for (int p=0;p<4;p++){
      int r = p*32 + row;
      async16(ybf + ((size_t)(m0+r) << 9) + k0 + ch8, &As[(r<<6) + ch8]);
      int br = n0 + (r & 63) + ((r >> 6) << 9);
      async16(owbf + ((size_t)br << 9) + k0 + ch8, &Bsh[(r<<6) + ch8]);
    }
    __syncthreads();
    #pragma unroll
    for (int ks=0;ks<2;ks++){
      s16x8 a[2], bf[8];
      #pragma unroll
      for (int mi=0;mi<2;mi++){
        uint4 t = *(const uint4*)(&As[(wave*32 + mi*16 + ro)*64 + ks*32 + qq*8]);
        a[mi] = __builtin_bit_cast(s16x8, t);
      }
      #pragma unroll
      for (int ni=0;ni<8;ni++){
        uint4 t = *(const uint4*)(&Bsh[(ni*16 + ro)*64 + ks*32 + qq*8]);
        bf[ni] = __builtin_bit_cast(s16x8, t);
      }
      #pragma unroll
      for (int mi=0;mi<2;mi++)
        #pragma unroll
        for (int ni=0;ni<8;ni++)
          acc[mi][ni] = __builtin_amdgcn_mfma_f32_16x16x32_bf16(a[mi], bf[ni], acc[mi][ni], 0, 0, 0);
    }
  }
  // epilogue: z1*sigmoid(z2) + residual
  #pragma unroll
  for (int ni=0;ni<4;ni++){
    int col = n0 + ni*16 + ro;
    float b1 = ob[col], b2 = ob[col + 512];
    #pragma unroll
    for (int mi=0;mi<2;mi++){
      f32x4 z1 = acc[mi][ni], z2 = acc[mi][ni+4];
      #pragma unroll
      for (int rg=0;rg<4;rg++){
        int rowi = m0 + wave*32 + mi*16 + qq*4 + rg;
        float zz1 = z1[rg] + b1;
        float zz2 = z2[rg] + b2;
        float g = zz1 / (1.f + expf(-zz2));
        size_t idx = ((size_t)rowi << 9) + col;
        hbuf[idx] += g;
      }
    }
  }
}

// ---------------- decoder ----------------------------------------------------------
__global__ __launch_bounds__(256) void decoder_kernel(
    const float* __restrict__ hbuf, const float* __restrict__ dec_w,
    const float* __restrict__ dec_b, float* __restrict__ out)
{
  int wid  = (int)((blockIdx.x*256 + threadIdx.x) >> 6);  // row id, 32768 total
  int lane = threadIdx.x & 63;
  const float* p = hbuf + ((size_t)wid << 9) + lane*8;
  float4 a = *(const float4*)p;
  float4 b = *(const float4*)(p+4);
  const float* dw = dec_w + lane*8;
  float4 w0 = *(const float4*)dw;
  float4 w1 = *(const float4*)(dw+4);
  float s = a.x*w0.x + a.y*w0.y + a.z*w0.z + a.w*w0.w
          + b.x*w1.x + b.y*w1.y + b.z*w1.z + b.w*w1.w;
  #pragma unroll
  for (int off=32; off; off>>=1) s += __shfl_xor(s, off, 64);
  if (lane == 0) out[wid] = s + dec_b[0];
}

extern "C" void kernel_launch(void* const* d_in, const int* in_sizes, int n_in,
                              void* d_out, int out_size, void* d_ws, size_t ws_size,
                              hipStream_t stream) {
  const float* x     = (const float*)d_in[0];
  const float* encw  = (const float*)d_in[1];
  const float* encb  = (const float*)d_in[2];
  const float* logdt = (const float*)d_in[3];
  const float* A_re  = (const float*)d_in[4];
  const float* A_im  = (const float*)d_in[5];
  const float* C_re  = (const float*)d_in[6];
  const float* C_im  = (const float*)d_in[7];
  const float* Dv    = (const float*)d_in[8];
  const float* out_w = (const float*)d_in[9];
  const float* out_b = (const float*)d_in[10];
  const float* ln_w  = (const float*)d_in[11];
  const float* ln_b  = (const float*)d_in[12];
  const float* dec_w = (const float*)d_in[13];
  const float* dec_b = (const float*)d_in[14];

  char* ws = (char*)d_ws;
  float*  hbuf   = (float*) (ws);                    //  64 MB
  float*  Sbuf   = (float*) (ws + 67108864);         //  67,108,864 B (NCH=64)
  float*  params = (float*) (ws + 134217728);        //   1 MB
  float2* stats  = (float2*)(ws + 135266304);        //   0.5 MB
  u16*    owbf   = (u16*)   (ws + 135790592);        //   4 MB
  u16*    ybf    = (u16*)   (ws + 139984896);        //  32 MB (end 173,539,328)
  float*  y32    = (float*) (ws + 173539328);        //  64 MB (end 240,648,192)
  const bool big_ws = (ws_size >= (size_t)240648192);

  param_kernel<<<128, 256, 0, stream>>>(logdt, A_re, A_im, C_re, C_im, params);
  owconv_kernel<<<8192, 256, 0, stream>>>(out_w, owbf);
  encoder_kernel<<<65536, 256, 0, stream>>>(x, encw, encb, hbuf);
  for (int layer=0; layer<NLAYER; ++layer){
    const float* P = params + layer*65536;
    stats_kernel<<<8192, 256, 0, stream>>>(hbuf, stats);
    phase1_kernel<<<8192, 64, 0, stream>>>(hbuf, stats, ln_w + layer*HD, ln_b + layer*HD, P, Sbuf);
    phase2_kernel<<<512, 256, 0, stream>>>(P, Sbuf);
    if (big_ws){
      phase3_kernel<<<4096, 64, 0, stream>>>(hbuf, stats, ln_w + layer*HD, ln_b + layer*HD,
                                             Dv + layer*HD, P, Sbuf, y32, ybf);
    } else {
      phase3_lds_kernel<<<4096, 64, 0, stream>>>(hbuf, stats, ln_w + layer*HD, ln_b + layer*HD,
                                                 Dv + layer*HD, P, Sbuf, ybf);
    }
    gemm_glu_kernel<<<2048, 256, 0, stream>>>(ybf, owbf + (size_t)layer*524288,
                                              out_b + layer*1024, hbuf);
  }
  decoder_kernel<<<8192, 256, 0, stream>>>(hbuf, dec_w, dec_b, (float*)d_out);
}

// Round 4
// 1083.805 us; speedup vs baseline: 1.1993x; 1.0752x over previous
//
#include <hip/hip_runtime.h>

// S4 model (B=8, L=4096, H=512, N=16, 4 layers), fully fused pipeline.
// Round 4:
//  - GEMM LDS XOR swizzle (kills 16-way bank conflicts while keeping the
//    lane-linear LDS layout global_load_lds requires).
//  - ustat kernel fuses LN into stats: writes bf16 normalized u (ubf);
//    phase1/phase3 read 2B/elem and skip LN math.
//  - ybf aliased onto ubf (read-before-write per element, block-exclusive
//    ranges) -> ws total 240,123,904 B (< proven 240,648,192 available).

typedef __attribute__((ext_vector_type(8))) short s16x8;
typedef __attribute__((ext_vector_type(4))) float f32x4;
typedef unsigned short u16;
typedef unsigned int u32;

#define LSEQ 4096
#define HD   512
#define NST  16
#define NLAYER 4
#define BS   8
#define LC   64
#define NCH  64   // LSEQ / LC

static __device__ __forceinline__ u16 f2bf(float f){
  u32 u = __builtin_bit_cast(u32, f);
  u += 0x7FFFu + ((u >> 16) & 1u);     // round-to-nearest-even
  return (u16)(u >> 16);
}
static __device__ __forceinline__ float bf2f(u16 v){
  u32 u = ((u32)v) << 16;
  return __builtin_bit_cast(float, u);
}

static __device__ __forceinline__ void async16(const void* g, void* l){
  __builtin_amdgcn_global_load_lds((const __attribute__((address_space(1))) unsigned*)g,
                                   (__attribute__((address_space(3))) unsigned*)l,
                                   16, 0, 0);
}

// ---------------- per-layer SSM params: w=exp(dt*A), w^LC, Ct=2*C*(w-1)/A ----------
// params layout per layer (65536 floats):
//   [0)      w  : n*1024 + {0,512} + h
//   [16384)  wLc: n*1024 + {0,512} + h
//   [32768)  Ct : (d*16+n)*1024 + {0,512} + h      (includes the factor 2)
__global__ __launch_bounds__(256) void param_kernel(
    const float* __restrict__ log_dt, const float* __restrict__ A_re,
    const float* __restrict__ A_im, const float* __restrict__ C_re,
    const float* __restrict__ C_im, float* __restrict__ params)
{
  int idx = blockIdx.x*256 + threadIdx.x;        // NLAYER*NST*HD = 32768
  int h = idx & (HD-1);
  int n = (idx >> 9) & (NST-1);
  int layer = idx >> 13;
  float dt  = expf(log_dt[layer*HD + h]);
  float Are = A_re[((layer<<9)+h)*NST + n];
  float Aim = A_im[((layer<<9)+h)*NST + n];
  float ar = Are*dt, ai = Aim*dt;
  float er = expf(ar), sn, cs;
  sincosf(ai, &sn, &cs);
  float wr = er*cs, wi = er*sn;
  float eL = expf((float)LC*ar), snL, csL;
  sincosf((float)LC*ai, &snL, &csL);
  float* P = params + layer*65536;
  P[n*1024 + h]        = wr;
  P[n*1024 + 512 + h]  = wi;
  P[16384 + n*1024 + h]       = eL*csL;
  P[16384 + n*1024 + 512 + h] = eL*snL;
  float den = Are*Are + Aim*Aim;
  float qr = ((wr-1.f)*Are + wi*Aim) / den;      // (w-1)/A = (w-1)*conj(A)/|A|^2
  float qi = (wi*Are - (wr-1.f)*Aim) / den;
  #pragma unroll
  for (int d=0; d<2; d++){
    float Cre = C_re[(((layer*2+d)<<9)+h)*NST + n];
    float Cim = C_im[(((layer*2+d)<<9)+h)*NST + n];
    P[32768 + (d*NST+n)*1024 + h]       = 2.f*(Cre*qr - Cim*qi);
    P[32768 + (d*NST+n)*1024 + 512 + h] = 2.f*(Cre*qi + Cim*qr);
  }
}

__global__ __launch_bounds__(256) void owconv_kernel(const float* __restrict__ ow,
                                                     u16* __restrict__ owbf)
{
  size_t idx = (size_t)blockIdx.x*256 + threadIdx.x;   // 4*1024*512 = 2,097,152
  owbf[idx] = f2bf(ow[idx]);
}

// ---------------- encoder ----------------------------------------------------------
__global__ __launch_bounds__(256) void encoder_kernel(
    const float* __restrict__ x, const float* __restrict__ ew,
    const float* __restrict__ eb, float* __restrict__ hbuf)
{
  size_t idx = (size_t)blockIdx.x*256 + threadIdx.x;   // B*L*H = 16,777,216
  int h = (int)(idx & (HD-1));
  int t = (int)((idx >> 9) & (LSEQ-1));
  int b = (int)(idx >> 21);
  float g = (float)t * (1.0f/4095.0f);
  hbuf[idx] = x[(b<<12) + t]*ew[2*h] + g*ew[2*h+1] + eb[h];
}

// ---------------- ustat: LN stats + write normalized u as bf16 ----------------------
// one wave per row; lane holds h = lane*8 .. lane*8+7
__global__ __launch_bounds__(256) void ustat_kernel(
    const float* __restrict__ hbuf, const float* __restrict__ lnw,
    const float* __restrict__ lnb, u16* __restrict__ ubf)
{
  int row  = (int)((blockIdx.x*256 + threadIdx.x) >> 6);  // 32768 rows
  int lane = threadIdx.x & 63;
  const float* p = hbuf + ((size_t)row << 9) + lane*8;
  float4 a = *(const float4*)p;
  float4 b = *(const float4*)(p+4);
  float s  = a.x+a.y+a.z+a.w + b.x+b.y+b.z+b.w;
  float sq = a.x*a.x+a.y*a.y+a.z*a.z+a.w*a.w + b.x*b.x+b.y*b.y+b.z*b.z+b.w*b.w;
  #pragma unroll
  for (int off=32; off; off>>=1){ s += __shfl_xor(s, off, 64); sq += __shfl_xor(sq, off, 64); }
  float mu = s*(1.f/512.f);
  float var = sq*(1.f/512.f) - mu*mu;
  float rstd = rsqrtf(var + 1e-5f);
  const float* wp = lnw + lane*8;
  const float* bp = lnb + lane*8;
  float4 w0 = *(const float4*)wp, w1 = *(const float4*)(wp+4);
  float4 b0 = *(const float4*)bp, b1 = *(const float4*)(bp+4);
  float u0 = (a.x-mu)*rstd*w0.x + b0.x;
  float u1 = (a.y-mu)*rstd*w0.y + b0.y;
  float u2 = (a.z-mu)*rstd*w0.z + b0.z;
  float u3 = (a.w-mu)*rstd*w0.w + b0.w;
  float u4 = (b.x-mu)*rstd*w1.x + b1.x;
  float u5 = (b.y-mu)*rstd*w1.y + b1.y;
  float u6 = (b.z-mu)*rstd*w1.z + b1.z;
  float u7 = (b.w-mu)*rstd*w1.w + b1.w;
  u32 o0 = (u32)f2bf(u0) | ((u32)f2bf(u1)<<16);
  u32 o1 = (u32)f2bf(u2) | ((u32)f2bf(u3)<<16);
  u32 o2 = (u32)f2bf(u4) | ((u32)f2bf(u5)<<16);
  u32 o3 = (u32)f2bf(u6) | ((u32)f2bf(u7)<<16);
  uint4 pk = make_uint4(o0,o1,o2,o3);
  *(uint4*)(ubf + ((size_t)row << 9) + lane*8) = pk;
}

// ---------------- phase 1: chunk summaries (both dirs) ------------------------------
// S layout: (((b*2+dir)*NCH + c)*NST + n)*1024 + {0,512} + h
__global__ __launch_bounds__(64) void phase1_kernel(
    const u16* __restrict__ ubf, const float* __restrict__ P, float* __restrict__ S)
{
  int bx = blockIdx.x;                  // ((b*2+dir)*NCH + c)*8 + hg ; 8192 blocks
  int hg  = bx & 7;
  int c   = (bx >> 3) & (NCH-1);
  int dir = (bx >> 9) & 1;
  int b   = bx >> 10;
  int lane = threadIdx.x;
  int hcol = (hg << 6) + lane;
  float wr[NST], wi[NST];
  #pragma unroll
  for (int n=0;n<NST;n++){ wr[n] = P[n*1024 + hcol]; wi[n] = P[n*1024 + 512 + hcol]; }
  float sr[NST], si[NST];
  #pragma unroll
  for (int n=0;n<NST;n++){ sr[n]=0.f; si[n]=0.f; }
  int t0 = c * LC;
  const u16* up = ubf + ((size_t)b << 21) + hcol;
  for (int j8=0; j8<LC; j8+=8){
    float uv[8];
    #pragma unroll
    for (int q=0;q<8;q++){
      int j = j8 + q;
      int t = dir ? (t0 + (LC-1) - j) : (t0 + j);
      uv[q] = bf2f(up[(size_t)t << 9]);
    }
    #pragma unroll
    for (int q=0;q<8;q++){
      float u = uv[q];
      #pragma unroll
      for (int n=0;n<NST;n++){
        float s0 = sr[n];
        sr[n] = fmaf(wr[n], s0, fmaf(-wi[n], si[n], u));
        si[n] = fmaf(wr[n], si[n], wi[n]*s0);
      }
    }
  }
  size_t sbase = (((size_t)(b*2+dir)*NCH + c)*NST)*1024 + hcol;
  #pragma unroll
  for (int n=0;n<NST;n++){
    S[sbase + (size_t)n*1024]       = sr[n];
    S[sbase + (size_t)n*1024 + 512] = si[n];
  }
}

// ---------------- phase 2: inter-chunk scan (in place on S) -------------------------
__global__ __launch_bounds__(256) void phase2_kernel(const float* __restrict__ P,
                                                     float* __restrict__ S)
{
  int f = blockIdx.x*256 + threadIdx.x;     // B*2*NST*HD = 131072
  int h   = f & (HD-1);
  int n   = (f >> 9) & (NST-1);
  int dir = (f >> 13) & 1;
  int b   = f >> 14;
  float wLr = P[16384 + n*1024 + h];
  float wLi = P[16384 + n*1024 + 512 + h];
  size_t base = (((size_t)(b*2+dir)*NCH)*NST + n)*1024 + h;
  const size_t cs = (size_t)NST*1024;       // floats per chunk
  float Xr = 0.f, Xi = 0.f;
  if (dir == 0){
    for (int c=0;c<NCH;c++){
      float Sr = S[base + c*cs], Si = S[base + c*cs + 512];
      float nr = fmaf(wLr, Xr, fmaf(-wLi, Xi, Sr));
      float ni = fmaf(wLr, Xi, fmaf( wLi, Xr, Si));
      Xr = nr; Xi = ni;
      S[base + c*cs] = Xr; S[base + c*cs + 512] = Xi;
    }
  } else {
    for (int cc=0;cc<NCH;cc++){
      int c = NCH-1-cc;
      float Sr = S[base + c*cs], Si = S[base + c*cs + 512];
      S[base + c*cs] = Xr; S[base + c*cs + 512] = Xi;   // boundary BEFORE update
      float nr = fmaf(wLr, Xr, fmaf(-wLi, Xi, Sr));
      float ni = fmaf(wLr, Xi, fmaf( wLi, Xr, Si));
      Xr = nr; Xi = ni;
    }
  }
}

// ---------------- phase 3: fwd writes y32; bwd reads, GELU, bf16 into uy ------------
// uy is BOTH the bf16 u input and the bf16 y output (exact same (b,t,h) slots;
// every element is read (fwd+bwd prefetch) before its bwd write; one pointer, so
// no restrict violation).
__global__ __launch_bounds__(64) void phase3_kernel(
    u16* __restrict__ uy, const float* __restrict__ Dvec, const float* __restrict__ P,
    const float* __restrict__ S, float* __restrict__ y32)
{
  int bx = blockIdx.x;                 // (b*NCH + c)*8 + hg ; 4096 blocks
  int hg = bx & 7;
  int c  = (bx >> 3) & (NCH-1);
  int b  = bx >> 9;
  int lane = threadIdx.x;
  int hcol = (hg << 6) + lane;
  float wr[NST], wi[NST];
  #pragma unroll
  for (int n=0;n<NST;n++){ wr[n] = P[n*1024 + hcol]; wi[n] = P[n*1024 + 512 + hcol]; }
  float Dh = Dvec[hcol];
  int t0 = c * LC;
  u16* up = uy + ((size_t)b << 21) + hcol;
  float* yp = y32 + ((size_t)b << 21) + hcol;

  // ---- forward: y32[t] = u*D + 2Re(Ct0 . x[t]) ----
  {
    float cr[NST], ci[NST], xr[NST], xi[NST];
    #pragma unroll
    for (int n=0;n<NST;n++){
      cr[n] = P[32768 + n*1024 + hcol];
      ci[n] = P[32768 + n*1024 + 512 + hcol];
    }
    if (c > 0){
      size_t sb = (((size_t)(b*2+0)*NCH + (c-1))*NST)*1024 + hcol;
      #pragma unroll
      for (int n=0;n<NST;n++){ xr[n] = S[sb + (size_t)n*1024]; xi[n] = S[sb + (size_t)n*1024 + 512]; }
    } else {
      #pragma unroll
      for (int n=0;n<NST;n++){ xr[n]=0.f; xi[n]=0.f; }
    }
    for (int j8=0;j8<LC;j8+=8){
      float uv[8];
      #pragma unroll
      for (int q=0;q<8;q++){
        int t = t0 + j8 + q;
        uv[q] = bf2f(up[(size_t)t << 9]);
      }
      #pragma unroll
      for (int q=0;q<8;q++){
        float u = uv[q];
        float acc = u*Dh;
        #pragma unroll
        for (int n=0;n<NST;n++){
          float s0 = xr[n];
          xr[n] = fmaf(wr[n], s0, fmaf(-wi[n], xi[n], u));
          xi[n] = fmaf(wr[n], xi[n], wi[n]*s0);
          acc = fmaf(cr[n], xr[n], acc);
          acc = fmaf(-ci[n], xi[n], acc);
        }
        yp[(size_t)(t0 + j8 + q) << 9] = acc;
      }
    }
  }
  // ---- backward: y = y32[t] + 2Re(Ct1 . xb[t]); GELU; bf16 store into uy ----
  {
    float cr[NST], ci[NST], xr[NST], xi[NST];
    #pragma unroll
    for (int n=0;n<NST;n++){
      cr[n] = P[32768 + (NST+n)*1024 + hcol];
      ci[n] = P[32768 + (NST+n)*1024 + 512 + hcol];
    }
    size_t sb = (((size_t)(b*2+1)*NCH + c)*NST)*1024 + hcol;
    #pragma unroll
    for (int n=0;n<NST;n++){ xr[n] = S[sb + (size_t)n*1024]; xi[n] = S[sb + (size_t)n*1024 + 512]; }
    for (int j8=0;j8<LC;j8+=8){
      float uv[8], yf[8];
      #pragma unroll
      for (int q=0;q<8;q++){
        int t = t0 + (LC-1) - (j8+q);
        uv[q] = bf2f(up[(size_t)t << 9]);   // read u BEFORE y overwrite below
        yf[q] = yp[(size_t)t << 9];
      }
      #pragma unroll
      for (int q=0;q<8;q++){
        int t = t0 + (LC-1) - (j8+q);
        float acc = yf[q];
        #pragma unroll
        for (int n=0;n<NST;n++){
          acc = fmaf(cr[n], xr[n], acc);
          acc = fmaf(-ci[n], xi[n], acc);
        }
        float g = 0.5f*acc*(1.f + erff(acc*0.70710678118654752f));
        up[(size_t)t << 9] = f2bf(g);
        float u = uv[q];
        #pragma unroll
        for (int n=0;n<NST;n++){
          float s0 = xr[n];
          xr[n] = fmaf(wr[n], s0, fmaf(-wi[n], xi[n], u));
          xi[n] = fmaf(wr[n], xi[n], wi[n]*s0);
        }
      }
    }
  }
}

// ---------------- GEMM (bf16 MFMA, swizzled global_load_lds staging) + GLU ----------
// LDS slot (r, c) holds global 16B-chunk (c ^ (r&7)) of row r -> conflict-free
// b128 reads (8 lanes per 16B column) while keeping lane-linear DMA dests.
__global__ __launch_bounds__(256) void gemm_glu_kernel(
    const u16* __restrict__ ybf, const u16* __restrict__ owbf,
    const float* __restrict__ ob, float* __restrict__ hbuf)
{
  __shared__ u16 As[128*64];
  __shared__ u16 Bsh[128*64];
  const int tid = threadIdx.x;
  const int wave = tid >> 6, lane = tid & 63;
  const int mt = blockIdx.x >> 3, nt = blockIdx.x & 7;
  const int m0 = mt*128, n0 = nt*64;
  const int row = tid >> 3;           // 0..31
  const int ch  = tid & 7;            // 16B chunk slot 0..7
  f32x4 acc[2][8];
  #pragma unroll
  for (int i=0;i<2;i++)
    #pragma unroll
    for (int j=0;j<8;j++)
      #pragma unroll
      for (int k=0;k<4;k++) acc[i][j][k] = 0.f;

  const int ro = lane & 15, qq = lane >> 4;
  const int sx = ro & 7;              // read-side swizzle key
  for (int k0=0;k0<512;k0+=64){
    __syncthreads();
    #pragma unroll
    for (int p=0;p<4;p++){
      int r = p*32 + row;
      int cs = (ch ^ (r & 7)) << 3;   // swizzled source chunk (u16 units)
      async16(ybf + ((size_t)(m0+r) << 9) + k0 + cs, &As[(r<<6) + (ch<<3)]);
      int br = n0 + (r & 63) + ((r >> 6) << 9);
      async16(owbf + ((size_t)br << 9) + k0 + cs, &Bsh[(r<<6) + (ch<<3)]);
    }
    __syncthreads();
    #pragma unroll
    for (int ks=0;ks<2;ks++){
      s16x8 a[2], bf[8];
      #pragma unroll
      for (int mi=0;mi<2;mi++){
        int g = ks*4 + qq;            // wanted global chunk
        uint4 t = *(const uint4*)(&As[((wave*32 + mi*16 + ro)<<6) + ((g ^ sx)<<3)]);
        a[mi] = __builtin_bit_cast(s16x8, t);
      }
      #pragma unroll
      for (int ni=0;ni<8;ni++){
        int g = ks*4 + qq;
        uint4 t = *(const uint4*)(&Bsh[((ni*16 + ro)<<6) + ((g ^ sx)<<3)]);
        bf[ni] = __builtin_bit_cast(s16x8, t);
      }
      #pragma unroll
      for (int mi=0;mi<2;mi++)
        #pragma unroll
        for (int ni=0;ni<8;ni++)
          acc[mi][ni] = __builtin_amdgcn_mfma_f32_16x16x32_bf16(a[mi], bf[ni], acc[mi][ni], 0, 0, 0);
    }
  }
  // epilogue: z1*sigmoid(z2) + residual
  #pragma unroll
  for (int ni=0;ni<4;ni++){
    int col = n0 + ni*16 + ro;
    float b1 = ob[col], b2 = ob[col + 512];
    #pragma unroll
    for (int mi=0;mi<2;mi++){
      f32x4 z1 = acc[mi][ni], z2 = acc[mi][ni+4];
      #pragma unroll
      for (int rg=0;rg<4;rg++){
        int rowi = m0 + wave*32 + mi*16 + qq*4 + rg;
        float zz1 = z1[rg] + b1;
        float zz2 = z2[rg] + b2;
        float g = zz1 / (1.f + expf(-zz2));
        size_t idx = ((size_t)rowi << 9) + col;
        hbuf[idx] += g;
      }
    }
  }
}

// ---------------- decoder ----------------------------------------------------------
__global__ __launch_bounds__(256) void decoder_kernel(
    const float* __restrict__ hbuf, const float* __restrict__ dec_w,
    const float* __restrict__ dec_b, float* __restrict__ out)
{
  int wid  = (int)((blockIdx.x*256 + threadIdx.x) >> 6);  // row id, 32768 total
  int lane = threadIdx.x & 63;
  const float* p = hbuf + ((size_t)wid << 9) + lane*8;
  float4 a = *(const float4*)p;
  float4 b = *(const float4*)(p+4);
  const float* dw = dec_w + lane*8;
  float4 w0 = *(const float4*)dw;
  float4 w1 = *(const float4*)(dw+4);
  float s = a.x*w0.x + a.y*w0.y + a.z*w0.z + a.w*w0.w
          + b.x*w1.x + b.y*w1.y + b.z*w1.z + b.w*w1.w;
  #pragma unroll
  for (int off=32; off; off>>=1) s += __shfl_xor(s, off, 64);
  if (lane == 0) out[wid] = s + dec_b[0];
}

extern "C" void kernel_launch(void* const* d_in, const int* in_sizes, int n_in,
                              void* d_out, int out_size, void* d_ws, size_t ws_size,
                              hipStream_t stream) {
  const float* x     = (const float*)d_in[0];
  const float* encw  = (const float*)d_in[1];
  const float* encb  = (const float*)d_in[2];
  const float* logdt = (const float*)d_in[3];
  const float* A_re  = (const float*)d_in[4];
  const float* A_im  = (const float*)d_in[5];
  const float* C_re  = (const float*)d_in[6];
  const float* C_im  = (const float*)d_in[7];
  const float* Dv    = (const float*)d_in[8];
  const float* out_w = (const float*)d_in[9];
  const float* out_b = (const float*)d_in[10];
  const float* ln_w  = (const float*)d_in[11];
  const float* ln_b  = (const float*)d_in[12];
  const float* dec_w = (const float*)d_in[13];
  const float* dec_b = (const float*)d_in[14];

  char* ws = (char*)d_ws;
  float*  hbuf   = (float*) (ws);                    //  64 MB
  float*  Sbuf   = (float*) (ws + 67108864);         //  64 MB   (end 134,217,728)
  float*  params = (float*) (ws + 134217728);        //   1 MB   (end 135,266,304)
  u16*    owbf   = (u16*)   (ws + 135266304);        //   4 MB   (end 139,460,608)
  u16*    uy     = (u16*)   (ws + 139460608);        //  32 MB   (end 173,015,040)  u AND y (aliased)
  float*  y32    = (float*) (ws + 173015040);        //  64 MB   (end 240,123,904)

  param_kernel<<<128, 256, 0, stream>>>(logdt, A_re, A_im, C_re, C_im, params);
  owconv_kernel<<<8192, 256, 0, stream>>>(out_w, owbf);
  encoder_kernel<<<65536, 256, 0, stream>>>(x, encw, encb, hbuf);
  for (int layer=0; layer<NLAYER; ++layer){
    const float* P = params + layer*65536;
    ustat_kernel<<<8192, 256, 0, stream>>>(hbuf, ln_w + layer*HD, ln_b + layer*HD, uy);
    phase1_kernel<<<8192, 64, 0, stream>>>(uy, P, Sbuf);
    phase2_kernel<<<512, 256, 0, stream>>>(P, Sbuf);
    phase3_kernel<<<4096, 64, 0, stream>>>(uy, Dv + layer*HD, P, Sbuf, y32);
    gemm_glu_kernel<<<2048, 256, 0, stream>>>(uy, owbf + (size_t)layer*524288,
                                              out_b + layer*1024, hbuf);
  }
  decoder_kernel<<<8192, 256, 0, stream>>>(hbuf, dec_w, dec_b, (float*)d_out);
}

// Round 5
// 1081.796 us; speedup vs baseline: 1.2016x; 1.0019x over previous
//
#include <hip/hip_runtime.h>

// S4 model (B=8, L=4096, H=512, N=16, 4 layers), fully fused pipeline.
// Round 5: packed-FP32 (v_pk_fma_f32) scan math in phase1/phase3 — SSM state
// pairs (n,n+1) packed into float2 vectors; halves VALU-issue count of the
// dominant kernels. Everything else unchanged from round 4.

typedef __attribute__((ext_vector_type(8))) short s16x8;
typedef __attribute__((ext_vector_type(4))) float f32x4;
typedef __attribute__((ext_vector_type(2))) float f32x2;
typedef unsigned short u16;
typedef unsigned int u32;

#define LSEQ 4096
#define HD   512
#define NST  16
#define NP   8     // NST/2 packed pairs
#define NLAYER 4
#define BS   8
#define LC   64
#define NCH  64   // LSEQ / LC

static __device__ __forceinline__ u16 f2bf(float f){
  u32 u = __builtin_bit_cast(u32, f);
  u += 0x7FFFu + ((u >> 16) & 1u);     // round-to-nearest-even
  return (u16)(u >> 16);
}
static __device__ __forceinline__ float bf2f(u16 v){
  u32 u = ((u32)v) << 16;
  return __builtin_bit_cast(float, u);
}
static __device__ __forceinline__ f32x2 pk_fma(f32x2 a, f32x2 b, f32x2 c){
#if __has_builtin(__builtin_elementwise_fma)
  return __builtin_elementwise_fma(a, b, c);
#else
  f32x2 r; r.x = fmaf(a.x,b.x,c.x); r.y = fmaf(a.y,b.y,c.y); return r;
#endif
}

static __device__ __forceinline__ void async16(const void* g, void* l){
  __builtin_amdgcn_global_load_lds((const __attribute__((address_space(1))) unsigned*)g,
                                   (__attribute__((address_space(3))) unsigned*)l,
                                   16, 0, 0);
}

// ---------------- per-layer SSM params: w=exp(dt*A), w^LC, Ct=2*C*(w-1)/A ----------
// params layout per layer (65536 floats):
//   [0)      w  : n*1024 + {0,512} + h
//   [16384)  wLc: n*1024 + {0,512} + h
//   [32768)  Ct : (d*16+n)*1024 + {0,512} + h      (includes the factor 2)
__global__ __launch_bounds__(256) void param_kernel(
    const float* __restrict__ log_dt, const float* __restrict__ A_re,
    const float* __restrict__ A_im, const float* __restrict__ C_re,
    const float* __restrict__ C_im, float* __restrict__ params)
{
  int idx = blockIdx.x*256 + threadIdx.x;        // NLAYER*NST*HD = 32768
  int h = idx & (HD-1);
  int n = (idx >> 9) & (NST-1);
  int layer = idx >> 13;
  float dt  = expf(log_dt[layer*HD + h]);
  float Are = A_re[((layer<<9)+h)*NST + n];
  float Aim = A_im[((layer<<9)+h)*NST + n];
  float ar = Are*dt, ai = Aim*dt;
  float er = expf(ar), sn, cs;
  sincosf(ai, &sn, &cs);
  float wr = er*cs, wi = er*sn;
  float eL = expf((float)LC*ar), snL, csL;
  sincosf((float)LC*ai, &snL, &csL);
  float* P = params + layer*65536;
  P[n*1024 + h]        = wr;
  P[n*1024 + 512 + h]  = wi;
  P[16384 + n*1024 + h]       = eL*csL;
  P[16384 + n*1024 + 512 + h] = eL*snL;
  float den = Are*Are + Aim*Aim;
  float qr = ((wr-1.f)*Are + wi*Aim) / den;      // (w-1)/A = (w-1)*conj(A)/|A|^2
  float qi = (wi*Are - (wr-1.f)*Aim) / den;
  #pragma unroll
  for (int d=0; d<2; d++){
    float Cre = C_re[(((layer*2+d)<<9)+h)*NST + n];
    float Cim = C_im[(((layer*2+d)<<9)+h)*NST + n];
    P[32768 + (d*NST+n)*1024 + h]       = 2.f*(Cre*qr - Cim*qi);
    P[32768 + (d*NST+n)*1024 + 512 + h] = 2.f*(Cre*qi + Cim*qr);
  }
}

__global__ __launch_bounds__(256) void owconv_kernel(const float* __restrict__ ow,
                                                     u16* __restrict__ owbf)
{
  size_t idx = (size_t)blockIdx.x*256 + threadIdx.x;   // 4*1024*512 = 2,097,152
  owbf[idx] = f2bf(ow[idx]);
}

// ---------------- encoder ----------------------------------------------------------
__global__ __launch_bounds__(256) void encoder_kernel(
    const float* __restrict__ x, const float* __restrict__ ew,
    const float* __restrict__ eb, float* __restrict__ hbuf)
{
  size_t idx = (size_t)blockIdx.x*256 + threadIdx.x;   // B*L*H = 16,777,216
  int h = (int)(idx & (HD-1));
  int t = (int)((idx >> 9) & (LSEQ-1));
  int b = (int)(idx >> 21);
  float g = (float)t * (1.0f/4095.0f);
  hbuf[idx] = x[(b<<12) + t]*ew[2*h] + g*ew[2*h+1] + eb[h];
}

// ---------------- ustat: LN stats + write normalized u as bf16 ----------------------
__global__ __launch_bounds__(256) void ustat_kernel(
    const float* __restrict__ hbuf, const float* __restrict__ lnw,
    const float* __restrict__ lnb, u16* __restrict__ ubf)
{
  int row  = (int)((blockIdx.x*256 + threadIdx.x) >> 6);  // 32768 rows
  int lane = threadIdx.x & 63;
  const float* p = hbuf + ((size_t)row << 9) + lane*8;
  float4 a = *(const float4*)p;
  float4 b = *(const float4*)(p+4);
  float s  = a.x+a.y+a.z+a.w + b.x+b.y+b.z+b.w;
  float sq = a.x*a.x+a.y*a.y+a.z*a.z+a.w*a.w + b.x*b.x+b.y*b.y+b.z*b.z+b.w*b.w;
  #pragma unroll
  for (int off=32; off; off>>=1){ s += __shfl_xor(s, off, 64); sq += __shfl_xor(sq, off, 64); }
  float mu = s*(1.f/512.f);
  float var = sq*(1.f/512.f) - mu*mu;
  float rstd = rsqrtf(var + 1e-5f);
  const float* wp = lnw + lane*8;
  const float* bp = lnb + lane*8;
  float4 w0 = *(const float4*)wp, w1 = *(const float4*)(wp+4);
  float4 b0 = *(const float4*)bp, b1 = *(const float4*)(bp+4);
  float u0 = (a.x-mu)*rstd*w0.x + b0.x;
  float u1 = (a.y-mu)*rstd*w0.y + b0.y;
  float u2 = (a.z-mu)*rstd*w0.z + b0.z;
  float u3 = (a.w-mu)*rstd*w0.w + b0.w;
  float u4 = (b.x-mu)*rstd*w1.x + b1.x;
  float u5 = (b.y-mu)*rstd*w1.y + b1.y;
  float u6 = (b.z-mu)*rstd*w1.z + b1.z;
  float u7 = (b.w-mu)*rstd*w1.w + b1.w;
  u32 o0 = (u32)f2bf(u0) | ((u32)f2bf(u1)<<16);
  u32 o1 = (u32)f2bf(u2) | ((u32)f2bf(u3)<<16);
  u32 o2 = (u32)f2bf(u4) | ((u32)f2bf(u5)<<16);
  u32 o3 = (u32)f2bf(u6) | ((u32)f2bf(u7)<<16);
  uint4 pk = make_uint4(o0,o1,o2,o3);
  *(uint4*)(ubf + ((size_t)row << 9) + lane*8) = pk;
}

// ---------------- phase 1: chunk summaries (both dirs), packed fp32 -----------------
// S layout: (((b*2+dir)*NCH + c)*NST + n)*1024 + {0,512} + h
__global__ __launch_bounds__(64) void phase1_kernel(
    const u16* __restrict__ ubf, const float* __restrict__ P, float* __restrict__ S)
{
  int bx = blockIdx.x;                  // ((b*2+dir)*NCH + c)*8 + hg ; 8192 blocks
  int hg  = bx & 7;
  int c   = (bx >> 3) & (NCH-1);
  int dir = (bx >> 9) & 1;
  int b   = bx >> 10;
  int lane = threadIdx.x;
  int hcol = (hg << 6) + lane;
  f32x2 wr2[NP], wn2[NP], wi2[NP];
  #pragma unroll
  for (int j=0;j<NP;j++){
    float wra = P[(2*j)*1024 + hcol],   wrb = P[(2*j+1)*1024 + hcol];
    float wia = P[(2*j)*1024 + 512 + hcol], wib = P[(2*j+1)*1024 + 512 + hcol];
    wr2[j] = (f32x2){wra, wrb};
    wi2[j] = (f32x2){wia, wib};
    wn2[j] = (f32x2){-wia, -wib};
  }
  f32x2 sr2[NP], si2[NP];
  #pragma unroll
  for (int j=0;j<NP;j++){ sr2[j]=(f32x2){0.f,0.f}; si2[j]=(f32x2){0.f,0.f}; }
  int t0 = c * LC;
  const u16* up = ubf + ((size_t)b << 21) + hcol;
  for (int j8=0; j8<LC; j8+=8){
    float uv[8];
    #pragma unroll
    for (int q=0;q<8;q++){
      int jj = j8 + q;
      int t = dir ? (t0 + (LC-1) - jj) : (t0 + jj);
      uv[q] = bf2f(up[(size_t)t << 9]);
    }
    #pragma unroll
    for (int q=0;q<8;q++){
      f32x2 u2 = (f32x2){uv[q], uv[q]};
      #pragma unroll
      for (int j=0;j<NP;j++){
        f32x2 s0 = sr2[j];
        sr2[j] = pk_fma(wr2[j], s0, pk_fma(wn2[j], si2[j], u2));
        si2[j] = pk_fma(wr2[j], si2[j], wi2[j]*s0);
      }
    }
  }
  size_t sbase = (((size_t)(b*2+dir)*NCH + c)*NST)*1024 + hcol;
  #pragma unroll
  for (int j=0;j<NP;j++){
    S[sbase + (size_t)(2*j)*1024]         = sr2[j].x;
    S[sbase + (size_t)(2*j)*1024 + 512]   = si2[j].x;
    S[sbase + (size_t)(2*j+1)*1024]       = sr2[j].y;
    S[sbase + (size_t)(2*j+1)*1024 + 512] = si2[j].y;
  }
}

// ---------------- phase 2: inter-chunk scan (in place on S) -------------------------
__global__ __launch_bounds__(256) void phase2_kernel(const float* __restrict__ P,
                                                     float* __restrict__ S)
{
  int f = blockIdx.x*256 + threadIdx.x;     // B*2*NST*HD = 131072
  int h   = f & (HD-1);
  int n   = (f >> 9) & (NST-1);
  int dir = (f >> 13) & 1;
  int b   = f >> 14;
  float wLr = P[16384 + n*1024 + h];
  float wLi = P[16384 + n*1024 + 512 + h];
  size_t base = (((size_t)(b*2+dir)*NCH)*NST + n)*1024 + h;
  const size_t cs = (size_t)NST*1024;       // floats per chunk
  float Xr = 0.f, Xi = 0.f;
  if (dir == 0){
    for (int c=0;c<NCH;c++){
      float Sr = S[base + c*cs], Si = S[base + c*cs + 512];
      float nr = fmaf(wLr, Xr, fmaf(-wLi, Xi, Sr));
      float ni = fmaf(wLr, Xi, fmaf( wLi, Xr, Si));
      Xr = nr; Xi = ni;
      S[base + c*cs] = Xr; S[base + c*cs + 512] = Xi;
    }
  } else {
    for (int cc=0;cc<NCH;cc++){
      int c = NCH-1-cc;
      float Sr = S[base + c*cs], Si = S[base + c*cs + 512];
      S[base + c*cs] = Xr; S[base + c*cs + 512] = Xi;   // boundary BEFORE update
      float nr = fmaf(wLr, Xr, fmaf(-wLi, Xi, Sr));
      float ni = fmaf(wLr, Xi, fmaf( wLi, Xr, Si));
      Xr = nr; Xi = ni;
    }
  }
}

// ---------------- phase 3: packed fp32; fwd->y32; bwd reads, GELU, bf16 into uy -----
// uy is BOTH the bf16 u input and the bf16 y output (read-before-write per slot).
__global__ __launch_bounds__(64) void phase3_kernel(
    u16* __restrict__ uy, const float* __restrict__ Dvec, const float* __restrict__ P,
    const float* __restrict__ S, float* __restrict__ y32)
{
  int bx = blockIdx.x;                 // (b*NCH + c)*8 + hg ; 4096 blocks
  int hg = bx & 7;
  int c  = (bx >> 3) & (NCH-1);
  int b  = bx >> 9;
  int lane = threadIdx.x;
  int hcol = (hg << 6) + lane;
  f32x2 wr2[NP], wn2[NP], wi2[NP];
  #pragma unroll
  for (int j=0;j<NP;j++){
    float wra = P[(2*j)*1024 + hcol],   wrb = P[(2*j+1)*1024 + hcol];
    float wia = P[(2*j)*1024 + 512 + hcol], wib = P[(2*j+1)*1024 + 512 + hcol];
    wr2[j] = (f32x2){wra, wrb};
    wi2[j] = (f32x2){wia, wib};
    wn2[j] = (f32x2){-wia, -wib};
  }
  float Dh = Dvec[hcol];
  int t0 = c * LC;
  u16* up = uy + ((size_t)b << 21) + hcol;
  float* yp = y32 + ((size_t)b << 21) + hcol;

  // ---- forward: y32[t] = u*D + 2Re(Ct0 . x[t]) ----
  {
    f32x2 cr2[NP], cn2[NP], xr2[NP], xi2[NP];
    #pragma unroll
    for (int j=0;j<NP;j++){
      cr2[j] = (f32x2){P[32768 + (2*j)*1024 + hcol],       P[32768 + (2*j+1)*1024 + hcol]};
      cn2[j] = (f32x2){-P[32768 + (2*j)*1024 + 512 + hcol], -P[32768 + (2*j+1)*1024 + 512 + hcol]};
    }
    if (c > 0){
      size_t sb = (((size_t)(b*2+0)*NCH + (c-1))*NST)*1024 + hcol;
      #pragma unroll
      for (int j=0;j<NP;j++){
        xr2[j] = (f32x2){S[sb + (size_t)(2*j)*1024],       S[sb + (size_t)(2*j+1)*1024]};
        xi2[j] = (f32x2){S[sb + (size_t)(2*j)*1024 + 512], S[sb + (size_t)(2*j+1)*1024 + 512]};
      }
    } else {
      #pragma unroll
      for (int j=0;j<NP;j++){ xr2[j]=(f32x2){0.f,0.f}; xi2[j]=(f32x2){0.f,0.f}; }
    }
    for (int j8=0;j8<LC;j8+=8){
      float uv[8];
      #pragma unroll
      for (int q=0;q<8;q++){
        int t = t0 + j8 + q;
        uv[q] = bf2f(up[(size_t)t << 9]);
      }
      #pragma unroll
      for (int q=0;q<8;q++){
        float u = uv[q];
        f32x2 u2 = (f32x2){u, u};
        f32x2 acc2 = (f32x2){u*Dh, 0.f};
        #pragma unroll
        for (int j=0;j<NP;j++){
          f32x2 s0 = xr2[j];
          xr2[j] = pk_fma(wr2[j], s0, pk_fma(wn2[j], xi2[j], u2));
          xi2[j] = pk_fma(wr2[j], xi2[j], wi2[j]*s0);
          acc2 = pk_fma(cr2[j], xr2[j], acc2);
          acc2 = pk_fma(cn2[j], xi2[j], acc2);
        }
        yp[(size_t)(t0 + j8 + q) << 9] = acc2.x + acc2.y;
      }
    }
  }
  // ---- backward: y = y32[t] + 2Re(Ct1 . xb[t]); GELU; bf16 store into uy ----
  {
    f32x2 cr2[NP], cn2[NP], xr2[NP], xi2[NP];
    #pragma unroll
    for (int j=0;j<NP;j++){
      cr2[j] = (f32x2){P[32768 + (NST+2*j)*1024 + hcol],        P[32768 + (NST+2*j+1)*1024 + hcol]};
      cn2[j] = (f32x2){-P[32768 + (NST+2*j)*1024 + 512 + hcol], -P[32768 + (NST+2*j+1)*1024 + 512 + hcol]};
    }
    size_t sb = (((size_t)(b*2+1)*NCH + c)*NST)*1024 + hcol;
    #pragma unroll
    for (int j=0;j<NP;j++){
      xr2[j] = (f32x2){S[sb + (size_t)(2*j)*1024],       S[sb + (size_t)(2*j+1)*1024]};
      xi2[j] = (f32x2){S[sb + (size_t)(2*j)*1024 + 512], S[sb + (size_t)(2*j+1)*1024 + 512]};
    }
    for (int j8=0;j8<LC;j8+=8){
      float uv[8], yf[8];
      #pragma unroll
      for (int q=0;q<8;q++){
        int t = t0 + (LC-1) - (j8+q);
        uv[q] = bf2f(up[(size_t)t << 9]);   // read u BEFORE y overwrite below
        yf[q] = yp[(size_t)t << 9];
      }
      #pragma unroll
      for (int q=0;q<8;q++){
        int t = t0 + (LC-1) - (j8+q);
        f32x2 acc2 = (f32x2){yf[q], 0.f};
        #pragma unroll
        for (int j=0;j<NP;j++){
          acc2 = pk_fma(cr2[j], xr2[j], acc2);
          acc2 = pk_fma(cn2[j], xi2[j], acc2);
        }
        float acc = acc2.x + acc2.y;
        float g = 0.5f*acc*(1.f + erff(acc*0.70710678118654752f));
        up[(size_t)t << 9] = f2bf(g);
        float u = uv[q];
        f32x2 u2 = (f32x2){u, u};
        #pragma unroll
        for (int j=0;j<NP;j++){
          f32x2 s0 = xr2[j];
          xr2[j] = pk_fma(wr2[j], s0, pk_fma(wn2[j], xi2[j], u2));
          xi2[j] = pk_fma(wr2[j], xi2[j], wi2[j]*s0);
        }
      }
    }
  }
}

// ---------------- GEMM (bf16 MFMA, swizzled global_load_lds staging) + GLU ----------
// LDS slot (r, c) holds global 16B-chunk (c ^ (r&7)) of row r -> conflict-free
// b128 reads (8 lanes per 16B column) while keeping lane-linear DMA dests.
__global__ __launch_bounds__(256) void gemm_glu_kernel(
    const u16* __restrict__ ybf, const u16* __restrict__ owbf,
    const float* __restrict__ ob, float* __restrict__ hbuf)
{
  __shared__ u16 As[128*64];
  __shared__ u16 Bsh[128*64];
  const int tid = threadIdx.x;
  const int wave = tid >> 6, lane = tid & 63;
  const int mt = blockIdx.x >> 3, nt = blockIdx.x & 7;
  const int m0 = mt*128, n0 = nt*64;
  const int row = tid >> 3;           // 0..31
  const int ch  = tid & 7;            // 16B chunk slot 0..7
  f32x4 acc[2][8];
  #pragma unroll
  for (int i=0;i<2;i++)
    #pragma unroll
    for (int j=0;j<8;j++)
      #pragma unroll
      for (int k=0;k<4;k++) acc[i][j][k] = 0.f;

  const int ro = lane & 15, qq = lane >> 4;
  const int sx = ro & 7;              // read-side swizzle key
  for (int k0=0;k0<512;k0+=64){
    __syncthreads();
    #pragma unroll
    for (int p=0;p<4;p++){
      int r = p*32 + row;
      int cs = (ch ^ (r & 7)) << 3;   // swizzled source chunk (u16 units)
      async16(ybf + ((size_t)(m0+r) << 9) + k0 + cs, &As[(r<<6) + (ch<<3)]);
      int br = n0 + (r & 63) + ((r >> 6) << 9);
      async16(owbf + ((size_t)br << 9) + k0 + cs, &Bsh[(r<<6) + (ch<<3)]);
    }
    __syncthreads();
    #pragma unroll
    for (int ks=0;ks<2;ks++){
      s16x8 a[2], bf[8];
      #pragma unroll
      for (int mi=0;mi<2;mi++){
        int g = ks*4 + qq;            // wanted global chunk
        uint4 t = *(const uint4*)(&As[((wave*32 + mi*16 + ro)<<6) + ((g ^ sx)<<3)]);
        a[mi] = __builtin_bit_cast(s16x8, t);
      }
      #pragma unroll
      for (int ni=0;ni<8;ni++){
        int g = ks*4 + qq;
        uint4 t = *(const uint4*)(&Bsh[((ni*16 + ro)<<6) + ((g ^ sx)<<3)]);
        bf[ni] = __builtin_bit_cast(s16x8, t);
      }
      #pragma unroll
      for (int mi=0;mi<2;mi++)
        #pragma unroll
        for (int ni=0;ni<8;ni++)
          acc[mi][ni] = __builtin_amdgcn_mfma_f32_16x16x32_bf16(a[mi], bf[ni], acc[mi][ni], 0, 0, 0);
    }
  }
  // epilogue: z1*sigmoid(z2) + residual
  #pragma unroll
  for (int ni=0;ni<4;ni++){
    int col = n0 + ni*16 + ro;
    float b1 = ob[col], b2 = ob[col + 512];
    #pragma unroll
    for (int mi=0;mi<2;mi++){
      f32x4 z1 = acc[mi][ni], z2 = acc[mi][ni+4];
      #pragma unroll
      for (int rg=0;rg<4;rg++){
        int rowi = m0 + wave*32 + mi*16 + qq*4 + rg;
        float zz1 = z1[rg] + b1;
        float zz2 = z2[rg] + b2;
        float g = zz1 / (1.f + expf(-zz2));
        size_t idx = ((size_t)rowi << 9) + col;
        hbuf[idx] += g;
      }
    }
  }
}

// ---------------- decoder ----------------------------------------------------------
__global__ __launch_bounds__(256) void decoder_kernel(
    const float* __restrict__ hbuf, const float* __restrict__ dec_w,
    const float* __restrict__ dec_b, float* __restrict__ out)
{
  int wid  = (int)((blockIdx.x*256 + threadIdx.x) >> 6);  // row id, 32768 total
  int lane = threadIdx.x & 63;
  const float* p = hbuf + ((size_t)wid << 9) + lane*8;
  float4 a = *(const float4*)p;
  float4 b = *(const float4*)(p+4);
  const float* dw = dec_w + lane*8;
  float4 w0 = *(const float4*)dw;
  float4 w1 = *(const float4*)(dw+4);
  float s = a.x*w0.x + a.y*w0.y + a.z*w0.z + a.w*w0.w
          + b.x*w1.x + b.y*w1.y + b.z*w1.z + b.w*w1.w;
  #pragma unroll
  for (int off=32; off; off>>=1) s += __shfl_xor(s, off, 64);
  if (lane == 0) out[wid] = s + dec_b[0];
}

extern "C" void kernel_launch(void* const* d_in, const int* in_sizes, int n_in,
                              void* d_out, int out_size, void* d_ws, size_t ws_size,
                              hipStream_t stream) {
  const float* x     = (const float*)d_in[0];
  const float* encw  = (const float*)d_in[1];
  const float* encb  = (const float*)d_in[2];
  const float* logdt = (const float*)d_in[3];
  const float* A_re  = (const float*)d_in[4];
  const float* A_im  = (const float*)d_in[5];
  const float* C_re  = (const float*)d_in[6];
  const float* C_im  = (const float*)d_in[7];
  const float* Dv    = (const float*)d_in[8];
  const float* out_w = (const float*)d_in[9];
  const float* out_b = (const float*)d_in[10];
  const float* ln_w  = (const float*)d_in[11];
  const float* ln_b  = (const float*)d_in[12];
  const float* dec_w = (const float*)d_in[13];
  const float* dec_b = (const float*)d_in[14];

  char* ws = (char*)d_ws;
  float*  hbuf   = (float*) (ws);                    //  64 MB
  float*  Sbuf   = (float*) (ws + 67108864);         //  64 MB   (end 134,217,728)
  float*  params = (float*) (ws + 134217728);        //   1 MB   (end 135,266,304)
  u16*    owbf   = (u16*)   (ws + 135266304);        //   4 MB   (end 139,460,608)
  u16*    uy     = (u16*)   (ws + 139460608);        //  32 MB   (end 173,015,040)  u AND y (aliased)
  float*  y32    = (float*) (ws + 173015040);        //  64 MB   (end 240,123,904)

  param_kernel<<<128, 256, 0, stream>>>(logdt, A_re, A_im, C_re, C_im, params);
  owconv_kernel<<<8192, 256, 0, stream>>>(out_w, owbf);
  encoder_kernel<<<65536, 256, 0, stream>>>(x, encw, encb, hbuf);
  for (int layer=0; layer<NLAYER; ++layer){
    const float* P = params + layer*65536;
    ustat_kernel<<<8192, 256, 0, stream>>>(hbuf, ln_w + layer*HD, ln_b + layer*HD, uy);
    phase1_kernel<<<8192, 64, 0, stream>>>(uy, P, Sbuf);
    phase2_kernel<<<512, 256, 0, stream>>>(P, Sbuf);
    phase3_kernel<<<4096, 64, 0, stream>>>(uy, Dv + layer*HD, P, Sbuf, y32);
    gemm_glu_kernel<<<2048, 256, 0, stream>>>(uy, owbf + (size_t)layer*524288,
                                              out_b + layer*1024, hbuf);
  }
  decoder_kernel<<<8192, 256, 0, stream>>>(hbuf, dec_w, dec_b, (float*)d_out);
}